// Round 2
// baseline (860.658 us; speedup 1.0000x reference)
//
#include <hip/hip_runtime.h>
#include <cstdint>

// ---------------------------------------------------------------------------
// SnLocalDecoder: B=4, n=48, C=32. Round-11 = R10 composition, reg-fixed:
//  R10's one-barrier composed k_vw was correct but VGPR blew up 88->248
//  (compiler overlapped v/w paths: two wc[32][4] caches + hoisted epilogues).
//  R11 rewrites k_vw as a DUAL-accumulator sweep: one pass over the LDS tile
//  feeds accv and accw together with weights streamed 4xfloat4 per channel
//  pair (no wc[] cache at all). MODE1: 2 dual-sweeps (t, tT); MODE0: 1
//  dual-sweep with (W0+W1)@Wr pre-summed in k_compose. __launch_bounds__(256,4)
//  caps VGPR at 128 (4 blocks/CU at 34.8KB LDS); sched_barrier(0) keeps the
//  epilogue loads from hoisting into the sweeps. k_z / k_mix / k_final as R10.
// ---------------------------------------------------------------------------

namespace {

constexpr int nB = 4, nN = 48, nC = 32;
constexpr int SJ_ = nN * nC;            // 1536
constexpr int SI_ = nN * SJ_;           // 73728
constexpr long SB_ = (long)nN * SI_;    // 3538944
constexpr int RP_ = 294912;             // rows-partial stride (2 partials)
constexpr int CP_ = 294912;             // cols-partial stride (2 partials)
constexpr int TP_ = 6144;               // tot-partial stride  (4 partials)

__device__ __forceinline__ void decodePos(int p, int& b, int& i, int& j, int& m) {
    m = p % nN; int r = p / nN;
    j = r % nN; r /= nN;
    i = r % nN; b = r / nN;
}

// ---------------------------------------------------------------------------
__global__ __launch_bounds__(256) void k_prep(const float* __restrict__ x,
                                              const void* __restrict__ maskp,
                                              float* __restrict__ vm,
                                              float* __restrict__ S)
{
    __shared__ float vmL[nB * nN];
    const int tid = threadIdx.x;
    const unsigned int w0 = *(const unsigned int*)maskp;
    const bool is_byte = (w0 == 0x01010101u);   // bool-byte layout
    if (tid < nB * nN) {
        int b = tid / nN, i = tid % nN;
        long idx = ((long)(b * nN + i) * nN + i) * nN + i;   // mask[b,i,i,i]
        int bit;
        if (is_byte) bit = (((const unsigned char*)maskp)[idx] != 0);
        else         bit = (((const int*)maskp)[idx] != 0);
        float f = bit ? 1.f : 0.f;
        vm[tid] = f; vmL[tid] = f;
    }
    __syncthreads();
    if (tid < nB * nC) {
        int b = tid >> 5, c = tid & 31;
        float s = 0.f;
        for (int j = 0; j < nN; ++j) s += x[(b * nN + j) * nC + c] * vmL[b * nN + j];
        S[tid] = s;
    }
}

// ---------------------------------------------------------------------------
// Compose basic-conv weights with Wv / Ww:  cW[blk][k][c][d] = Wb[k]@Wr,
// cb[blk][d] = b@Wr.  blk: 0=L0v 1=L0w 2=L1v 3=L1w.
// Also cWs[blk][c][d] = (Wb[0]+Wb[1])@Wr for blk 0,1 (layer-0 symmetric t).
__global__ __launch_bounds__(256) void k_compose(
    const float* __restrict__ Wb0, const float* __restrict__ bb0,
    const float* __restrict__ Wv0, const float* __restrict__ Ww0,
    const float* __restrict__ Wb1, const float* __restrict__ bb1,
    const float* __restrict__ Wv1, const float* __restrict__ Ww1,
    float* __restrict__ cW, float* __restrict__ cb, float* __restrict__ cWs)
{
    const int blk = blockIdx.x;              // 0..3
    const float* Wb = (blk < 2) ? Wb0 : Wb1;
    const float* bb = (blk < 2) ? bb0 : bb1;
    const float* Wr = (blk == 0) ? Wv0 : (blk == 1) ? Ww0 : (blk == 2) ? Wv1 : Ww1;
    __shared__ float Ws[1024];
    const int tid = threadIdx.x;
    for (int q = tid; q < 1024; q += 256) Ws[q] = Wr[q];
    __syncthreads();
    for (int q = tid; q < 6144; q += 256) {
        const int d = q & 31;
        const float* row = Wb + (q >> 5) * 32;   // (k*32+c2) row, stride 32
        float s = 0.f;
        #pragma unroll
        for (int e = 0; e < 32; ++e) s = fmaf(row[e], Ws[e * 32 + d], s);
        cW[blk * 6144 + q] = s;
    }
    if (blk < 2) {
        for (int q = tid; q < 1024; q += 256) {
            const int d = q & 31; const int c = q >> 5;
            const float* r0 = Wb + c * 32;           // k=0 row
            const float* r1 = Wb + 1024 + c * 32;    // k=1 row
            float s = 0.f;
            #pragma unroll
            for (int e = 0; e < 32; ++e) s = fmaf(r0[e] + r1[e], Ws[e * 32 + d], s);
            cWs[blk * 1024 + q] = s;
        }
    }
    if (tid < 32) {
        float s = 0.f;
        #pragma unroll
        for (int e = 0; e < 32; ++e) s = fmaf(bb[e], Ws[e * 32 + tid], s);
        cb[blk * 32 + tid] = s;
    }
}

// ---------------------------------------------------------------------------
// Layer-0 small snconv2 terms, closed form from x and S.
__global__ __launch_bounds__(256) void k_mix0(
    const float* __restrict__ x, const float* __restrict__ S,
    const float* __restrict__ Wb, const float* __restrict__ bias,
    float* __restrict__ drp, float* __restrict__ ccp, float* __restrict__ tbp)
{
    __shared__ float W2s[1024], W3s[1024], W4s[1024], W5s[1024], bs[32];
    const int tid = threadIdx.x;
    for (int q = tid; q < 1024; q += 256) {
        W2s[q] = Wb[2048 + q]; W3s[q] = Wb[3072 + q];
        W4s[q] = Wb[4096 + q]; W5s[q] = Wb[5120 + q];
    }
    if (tid < 32) bs[tid] = bias[tid];
    __syncthreads();
    const int id = blockIdx.x * 256 + tid;        // (b*48+i)*48+m
    const int m = id % nN; int r = id / nN; const int i = r % nN; const int b = r / nN;
    float odr[32], occ[32];
    #pragma unroll
    for (int d = 0; d < 32; ++d) { odr[d] = 0.f; occ[d] = 0.f; }
    for (int c2 = 0; c2 < 32; ++c2) {
        float xi = x[(b * nN + i) * nC + c2];
        float xm = x[(b * nN + m) * nC + c2];
        float sc = S[b * nC + c2];
        float A = xi * xi * xm;
        float R = xi * xm * sc * (1.f / nN);
        #pragma unroll
        for (int d = 0; d < 32; ++d) {
            odr[d] = fmaf(A, W2s[c2 * 32 + d], fmaf(R, W3s[c2 * 32 + d], odr[d]));
            occ[d] = fmaf(R, W4s[c2 * 32 + d], occ[d]);
        }
    }
    #pragma unroll
    for (int d = 0; d < 32; d += 4) {
        *(float4*)(drp + (size_t)id * 32 + d) = make_float4(odr[d], odr[d+1], odr[d+2], odr[d+3]);
        *(float4*)(ccp + (size_t)id * 32 + d) = make_float4(occ[d], occ[d+1], occ[d+2], occ[d+3]);
    }
    if (i == 0) {
        float ot[32];
        #pragma unroll
        for (int d = 0; d < 32; ++d) ot[d] = bs[d];
        for (int c2 = 0; c2 < 32; ++c2) {
            float xm = x[(b * nN + m) * nC + c2];
            float sc = S[b * nC + c2];
            float Tc = xm * sc * sc * (1.f / (nN * nN));
            #pragma unroll
            for (int d = 0; d < 32; ++d) ot[d] = fmaf(Tc, W5s[c2 * 32 + d], ot[d]);
        }
        for (int d = 0; d < 32; d += 4)
            *(float4*)(tbp + (size_t)(b * nN + m) * 32 + d) = make_float4(ot[d], ot[d+1], ot[d+2], ot[d+3]);
    }
}

// ---------------------------------------------------------------------------
// Small snconv2 terms from k_z's partial reductions (2 rows, 2 cols, 4 tot).
template <int DOUT>
__global__ __launch_bounds__(256) void k_mix(
    const float* __restrict__ dgp, const float* __restrict__ rw2,
    const float* __restrict__ cl2, const float* __restrict__ tt4,
    const float* __restrict__ Wb, const float* __restrict__ bias,
    float* __restrict__ drp, float* __restrict__ ccp, float* __restrict__ tbp)
{
    __shared__ float W2s[32 * DOUT], W3s[32 * DOUT], W4s[32 * DOUT], W5s[32 * DOUT], bs[DOUT];
    const int tid = threadIdx.x;
    for (int q = tid; q < 32 * DOUT; q += 256) {
        W2s[q] = Wb[2 * 32 * DOUT + q]; W3s[q] = Wb[3 * 32 * DOUT + q];
        W4s[q] = Wb[4 * 32 * DOUT + q]; W5s[q] = Wb[5 * 32 * DOUT + q];
    }
    if (tid < DOUT) bs[tid] = bias[tid];
    __syncthreads();
    const int id = blockIdx.x * 256 + tid;
    const int m = id % nN; int r = id / nN; const int i = r % nN; const int b = r / nN;
    float odr[DOUT], occ[DOUT];
    #pragma unroll
    for (int d = 0; d < DOUT; ++d) { odr[d] = 0.f; occ[d] = 0.f; }
    for (int c2 = 0; c2 < 32; ++c2) {
        size_t q = (size_t)id * 32 + c2;
        float dg = dgp[q];
        float rw = (rw2[q] + rw2[q + RP_]) * (1.f / nN);
        float cl = (cl2[q] + cl2[q + CP_]) * (1.f / nN);
        #pragma unroll
        for (int d = 0; d < DOUT; ++d) {
            odr[d] = fmaf(dg, W2s[c2 * DOUT + d], fmaf(rw, W3s[c2 * DOUT + d], odr[d]));
            occ[d] = fmaf(cl, W4s[c2 * DOUT + d], occ[d]);
        }
    }
    #pragma unroll
    for (int d = 0; d < DOUT; d += 4) {
        *(float4*)(drp + (size_t)id * DOUT + d) = make_float4(odr[d], odr[d+1], odr[d+2], odr[d+3]);
        *(float4*)(ccp + (size_t)id * DOUT + d) = make_float4(occ[d], occ[d+1], occ[d+2], occ[d+3]);
    }
    if (i == 0) {
        float ot[DOUT];
        #pragma unroll
        for (int d = 0; d < DOUT; ++d) ot[d] = bs[d];
        for (int c2 = 0; c2 < 32; ++c2) {
            size_t q = (size_t)(b * nN + m) * 32 + c2;
            float tv = (tt4[q] + tt4[q + TP_] + tt4[q + 2 * TP_] + tt4[q + 3 * TP_])
                       * (1.f / (nN * nN));
            #pragma unroll
            for (int d = 0; d < DOUT; ++d) ot[d] = fmaf(tv, W5s[c2 * DOUT + d], ot[d]);
        }
        for (int d = 0; d < DOUT; d += 4)
            *(float4*)(tbp + (size_t)(b * nN + m) * DOUT + d) = make_float4(ot[d], ot[d+1], ot[d+2], ot[d+3]);
    }
}

// ---------------------------------------------------------------------------
// Composed-weight v/w producer, dual-accumulator:
//   v = mk * ( t@(W0@Wv) + tT@(W1@Wv) + drv + ccv + tbv ) + bv    (w alike)
// One barrier; each LDS value read once and FMA'd into BOTH accv and accw;
// weights streamed 4x float4 per channel pair (no register weight cache).
#define FMA4(ar, tv, w4)                       \
    ar[0] = fmaf(tv, w4.x, ar[0]);             \
    ar[1] = fmaf(tv, w4.y, ar[1]);             \
    ar[2] = fmaf(tv, w4.z, ar[2]);             \
    ar[3] = fmaf(tv, w4.w, ar[3]);

template <int MODE>
__global__ __launch_bounds__(256, 4) void k_vw(
    const float* __restrict__ src, const float* __restrict__ vm,
    const float* __restrict__ drv, const float* __restrict__ ccv, const float* __restrict__ tbv,
    const float* __restrict__ drw, const float* __restrict__ ccw, const float* __restrict__ tbw,
    const float* __restrict__ WAv, const float* __restrict__ WBv,
    const float* __restrict__ WAw, const float* __restrict__ WBw,
    const float* __restrict__ bv, const float* __restrict__ bw,
    float* __restrict__ vout, float* __restrict__ wout)
{
    __shared__ float sA[128 * 34];
    __shared__ float sB[(MODE == 0) ? 64 : 128 * 34];
    const int tid = threadIdx.x;
    const long base = (long)blockIdx.x * 128;

    if (MODE == 0) {
        for (int rep = 0; rep < 4; ++rep) {
            int q = rep * 256 + tid; int pl = q >> 3, cq = q & 7;
            int p = (int)base + pl;
            int b, i, j, m; decodePos(p, b, i, j, m);
            float4 xi = *(const float4*)(src + (size_t)(b * nN + i) * nC + cq * 4);
            float4 xj = *(const float4*)(src + (size_t)(b * nN + j) * nC + cq * 4);
            float4 xm = *(const float4*)(src + (size_t)(b * nN + m) * nC + cq * 4);
            int o = pl * 34 + cq * 4;
            sA[o + 0] = xi.x * xj.x * xm.x;
            sA[o + 1] = xi.y * xj.y * xm.y;
            sA[o + 2] = xi.z * xj.z * xm.z;
            sA[o + 3] = xi.w * xj.w * xm.w;
        }
    } else {
        for (int rep = 0; rep < 4; ++rep) {
            int q = rep * 256 + tid; int pl = q >> 3, cq = q & 7;
            long p = base + pl;
            float4 a = *(const float4*)(src + p * nC + cq * 4);
            int o = pl * 34 + cq * 4;
            sA[o + 0] = a.x; sA[o + 1] = a.y; sA[o + 2] = a.z; sA[o + 3] = a.w;
            int b, i, j, m; decodePos((int)p, b, i, j, m);
            long pT = ((long)(b * nN + j) * nN + i) * nN + m;
            float4 t4 = *(const float4*)(src + pT * nC + cq * 4);
            sB[o + 0] = t4.x; sB[o + 1] = t4.y; sB[o + 2] = t4.z; sB[o + 3] = t4.w;
        }
    }
    __syncthreads();                         // the ONLY barrier

    const int pt = tid >> 3, dq = tid & 7;
    const int p0 = pt * 4, d0 = dq * 4;
    float accv[4][4], accw[4][4];
    #pragma unroll
    for (int l = 0; l < 4; ++l)
        #pragma unroll
        for (int d = 0; d < 4; ++d) { accv[l][d] = 0.f; accw[l][d] = 0.f; }

    auto sweep_dual = [&](const float* sp, const float* Wv_, const float* Ww_) {
        #pragma unroll
        for (int cp = 0; cp < 16; ++cp) {
            float2 t0 = *(const float2*)(sp + (p0 + 0) * 34 + cp * 2);
            float2 t1 = *(const float2*)(sp + (p0 + 1) * 34 + cp * 2);
            float2 t2 = *(const float2*)(sp + (p0 + 2) * 34 + cp * 2);
            float2 t3 = *(const float2*)(sp + (p0 + 3) * 34 + cp * 2);
            const int c0 = cp * 2, c1 = cp * 2 + 1;
            float4 wv0 = *(const float4*)(Wv_ + c0 * nC + d0);
            float4 wv1 = *(const float4*)(Wv_ + c1 * nC + d0);
            float4 ww0 = *(const float4*)(Ww_ + c0 * nC + d0);
            float4 ww1 = *(const float4*)(Ww_ + c1 * nC + d0);
            FMA4(accv[0], t0.x, wv0); FMA4(accv[1], t1.x, wv0);
            FMA4(accv[2], t2.x, wv0); FMA4(accv[3], t3.x, wv0);
            FMA4(accv[0], t0.y, wv1); FMA4(accv[1], t1.y, wv1);
            FMA4(accv[2], t2.y, wv1); FMA4(accv[3], t3.y, wv1);
            FMA4(accw[0], t0.x, ww0); FMA4(accw[1], t1.x, ww0);
            FMA4(accw[2], t2.x, ww0); FMA4(accw[3], t3.x, ww0);
            FMA4(accw[0], t0.y, ww1); FMA4(accw[1], t1.y, ww1);
            FMA4(accw[2], t2.y, ww1); FMA4(accw[3], t3.y, ww1);
        }
    };
    auto epilogue = [&](float (*acc)[4],
                        const float* drp, const float* ccp, const float* tbp,
                        const float* bp, float* outp) {
        float4 b4 = *(const float4*)(bp + d0);
        #pragma unroll
        for (int l = 0; l < 4; ++l) {
            int p = (int)base + p0 + l;
            int b, i, j, m; decodePos(p, b, i, j, m);
            float4 d4 = *(const float4*)(drp + (size_t)((b * nN + i) * nN + m) * nC + d0);
            float4 c4 = *(const float4*)(ccp + (size_t)((b * nN + j) * nN + m) * nC + d0);
            float4 t4 = *(const float4*)(tbp + (size_t)(b * nN + m) * nC + d0);
            float mk = vm[b * nN + i] * vm[b * nN + j] * vm[b * nN + m];
            float4 o4;
            o4.x = (acc[l][0] + d4.x + c4.x + t4.x) * mk + b4.x;
            o4.y = (acc[l][1] + d4.y + c4.y + t4.y) * mk + b4.y;
            o4.z = (acc[l][2] + d4.z + c4.z + t4.z) * mk + b4.z;
            o4.w = (acc[l][3] + d4.w + c4.w + t4.w) * mk + b4.w;
            *(float4*)(outp + (size_t)(base + p0 + l) * nC + d0) = o4;
        }
    };

    if (MODE == 0) {
        sweep_dual(sA, WAv, WAw);            // weights pre-summed (W0+W1)@Wr
    } else {
        sweep_dual(sA, WAv, WAw);
        sweep_dual(sB, WBv, WBw);
    }
    __builtin_amdgcn_sched_barrier(0);       // keep epilogue loads out of sweeps
    epilogue(accv, drv, ccv, tbv, bv, vout);
    __builtin_amdgcn_sched_barrier(0);       // keep w-epilogue from fusing into v
    epilogue(accw, drw, ccw, tbw, bw, wout);
}

// ---------------------------------------------------------------------------
// z = V*W/n per (b,m); o-mix + relu + mask -> t; fused rows/cols/diag/tot
// partial reductions (no atomics). Tile 24i x 24j x 32c; 768 blocks.
__global__ __launch_bounds__(256, 3) void k_z(
    const float* __restrict__ v, const float* __restrict__ w,
    const float* __restrict__ Wo, const float* __restrict__ bo,
    const float* __restrict__ vm, float* __restrict__ tout,
    float* __restrict__ rows2, float* __restrict__ cols2,
    float* __restrict__ diag_, float* __restrict__ tot4)
{
    __shared__ float lds[12912];           // 51648 B -> 3 blocks/CU
    float* Vt = lds;                       // [kk][c][i]: kk*807 + c*25 + i
    float* Wt = lds + 6456;
    constexpr int ZS = 34;                 // z/out row stride (per position)
    constexpr int ZWO = 9792;              // Wo area
    constexpr int TOT0 = 10816;            // tot scratch [8][32]
    const int tid = threadIdx.x;
    const int blk = blockIdx.x;
    const int tl = blk & 3; const int bm = blk >> 2;
    const int it = tl >> 1, jt = tl & 1;
    const int b = bm / nN, m = bm % nN;
    const int c = tid & 31;
    const int g = tid >> 5;
    const int i3 = g >> 1, j2 = g & 1;     // i3 wave-uniform
    const int il0 = i3 * 6, jl0 = j2 * 12;
    const size_t posbase = (size_t)b * SB_ + (size_t)m * nC;

    float acc[6][12];
    #pragma unroll
    for (int l = 0; l < 6; ++l)
        #pragma unroll
        for (int u = 0; u < 12; ++u) acc[l][u] = 0.f;

    for (int kc = 0; kc < 6; ++kc) {
        if (kc) __syncthreads();
        #pragma unroll
        for (int rr = 0; rr < 6; ++rr) {          // V: 24i x 8k x 32c
            int q = rr * 256 + tid; int pos = q >> 3, cq = q & 7;
            int ii = pos >> 3, kk = pos & 7;
            float4 a = *(const float4*)(v + posbase + (size_t)(it * 24 + ii) * SI_
                                          + (size_t)(kc * 8 + kk) * SJ_ + cq * 4);
            float* dst = Vt + kk * 807 + (cq * 4) * 25 + ii;
            dst[0] = a.x; dst[25] = a.y; dst[50] = a.z; dst[75] = a.w;
        }
        #pragma unroll
        for (int rr = 0; rr < 6; ++rr) {          // W: 8k x 24j x 32c
            int q = rr * 256 + tid; int pos = q >> 3, cq = q & 7;
            int kk = pos / 24, jj = pos - kk * 24;
            float4 a = *(const float4*)(w + posbase + (size_t)(kc * 8 + kk) * SI_
                                          + (size_t)(jt * 24 + jj) * SJ_ + cq * 4);
            float* dst = Wt + kk * 807 + (cq * 4) * 25 + jj;
            dst[0] = a.x; dst[25] = a.y; dst[50] = a.z; dst[75] = a.w;
        }
        __syncthreads();
        #pragma unroll
        for (int kk = 0; kk < 8; ++kk) {
            float vf[6], wf[12];
            #pragma unroll
            for (int l = 0; l < 6; ++l) vf[l] = Vt[kk * 807 + c * 25 + il0 + l];
            #pragma unroll
            for (int u = 0; u < 12; ++u) wf[u] = Wt[kk * 807 + c * 25 + jl0 + u];
            #pragma unroll
            for (int l = 0; l < 6; ++l)
                #pragma unroll
                for (int u = 0; u < 12; ++u)
                    acc[l][u] = fmaf(vf[l], wf[u], acc[l][u]);
        }
    }
    __syncthreads();                               // staging area now reusable

    #pragma unroll
    for (int e = 0; e < 4; ++e)                    // Wo * (1/48)
        lds[ZWO + e * 256 + tid] = Wo[e * 256 + tid] * (1.f / nN);

    const int ptE = tid >> 3, dqE = tid & 7, d0 = dqE * 4;
    const float4 b4 = *(const float4*)(bo + d0);
    const float vmm = vm[b * nN + m];
    float colacc[3] = {0.f, 0.f, 0.f};
    float totacc = 0.f;

    for (int h = 0; h < 2; ++h) {
        if (h) __syncthreads();                    // protect h=0 reduction reads
        if ((i3 >> 1) == h) {                      // write this half's z
            int r0 = il0 - 12 * h;                 // 0 or 6
            #pragma unroll
            for (int l = 0; l < 6; ++l)
                #pragma unroll
                for (int u = 0; u < 12; ++u)
                    lds[((r0 + l) * 24 + jl0 + u) * ZS + c] = acc[l][u];
        }
        __syncthreads();                           // z + wo visible

        float oac[9][4];
        #pragma unroll
        for (int u = 0; u < 9; ++u)
            #pragma unroll
            for (int d = 0; d < 4; ++d) oac[u][d] = 0.f;
        #pragma unroll
        for (int c2 = 0; c2 < 32; ++c2) {
            float4 wo4 = *(const float4*)(lds + ZWO + c2 * 32 + d0);
            float zv[9];
            #pragma unroll
            for (int u = 0; u < 9; ++u) zv[u] = lds[(ptE * 9 + u) * ZS + c2];
            #pragma unroll
            for (int u = 0; u < 9; ++u) {
                oac[u][0] = fmaf(zv[u], wo4.x, oac[u][0]);
                oac[u][1] = fmaf(zv[u], wo4.y, oac[u][1]);
                oac[u][2] = fmaf(zv[u], wo4.z, oac[u][2]);
                oac[u][3] = fmaf(zv[u], wo4.w, oac[u][3]);
            }
        }
        __syncthreads();                           // all z reads done

        #pragma unroll
        for (int u = 0; u < 9; ++u) {
            int p = ptE * 9 + u;
            int rl = p / 24, jl = p - rl * 24;
            int gi = it * 24 + 12 * h + rl, gj = jt * 24 + jl;
            float mk = vm[b * nN + gi] * vm[b * nN + gj] * vmm;
            float4 o4;
            o4.x = fmaxf(oac[u][0] + b4.x, 0.f) * mk;
            o4.y = fmaxf(oac[u][1] + b4.y, 0.f) * mk;
            o4.z = fmaxf(oac[u][2] + b4.z, 0.f) * mk;
            o4.w = fmaxf(oac[u][3] + b4.w, 0.f) * mk;
            *(float4*)(tout + posbase + (size_t)gi * SI_ + (size_t)gj * SJ_ + d0) = o4;
            *(float2*)(lds + p * ZS + d0) = make_float2(o4.x, o4.y);
            *(float2*)(lds + p * ZS + d0 + 2) = make_float2(o4.z, o4.w);
        }
        __syncthreads();                           // out tile visible in LDS

        for (int rd = 0; rd < 2; ++rd) {
            int task = rd * 256 + tid;
            if (task < 384) {
                int i_r = task >> 5, c_r = task & 31;
                float rsum = 0.f;
                #pragma unroll
                for (int jl = 0; jl < 24; ++jl) rsum += lds[(i_r * 24 + jl) * ZS + c_r];
                int gi = it * 24 + 12 * h + i_r;
                rows2[(size_t)jt * RP_ + ((size_t)(b * nN + gi) * nN + m) * nC + c_r] = rsum;
                totacc += rsum;
                if (it == jt)
                    diag_[((size_t)(b * nN + gi) * nN + m) * nC + c_r] =
                        lds[(i_r * 24 + (12 * h + i_r)) * ZS + c_r];
            }
        }
        #pragma unroll
        for (int rr = 0; rr < 3; ++rr) {
            int task = rr * 256 + tid;
            int jl = task >> 5, c_c = task & 31;
            float csum = 0.f;
            #pragma unroll
            for (int il = 0; il < 12; ++il) csum += lds[(il * 24 + jl) * ZS + c_c];
            colacc[rr] += csum;
        }
    }

    #pragma unroll
    for (int rr = 0; rr < 3; ++rr) {
        int task = rr * 256 + tid;
        int jl = task >> 5, c_c = task & 31;
        cols2[(size_t)it * CP_ + ((size_t)(b * nN + jt * 24 + jl) * nN + m) * nC + c_c] = colacc[rr];
    }
    lds[TOT0 + g * 32 + c] = totacc;
    __syncthreads();
    if (tid < 32) {
        float s = 0.f;
        #pragma unroll
        for (int gg = 0; gg < 8; ++gg) s += lds[TOT0 + gg * 32 + tid];
        tot4[(size_t)(it * 2 + jt) * TP_ + (size_t)(b * nN + m) * nC + tid] = s;
    }
}

// ---------------------------------------------------------------------------
// Final snconv2 (C_out = 16), masked, direct to d_out. b64 sweeps.
__global__ __launch_bounds__(256) void k_final(
    const float* __restrict__ t, const float* __restrict__ vm,
    const float* __restrict__ drp, const float* __restrict__ ccp, const float* __restrict__ tbp,
    const float* __restrict__ W0, const float* __restrict__ W1,
    float* __restrict__ out)
{
    __shared__ float sA[128 * 34], sB[128 * 34];
    const int tid = threadIdx.x;
    const long base = (long)blockIdx.x * 128;
    for (int rep = 0; rep < 4; ++rep) {
        int q = rep * 256 + tid; int pl = q >> 3, cq = q & 7;
        long p = base + pl;
        float4 a = *(const float4*)(t + p * nC + cq * 4);
        int o = pl * 34 + cq * 4;
        sA[o + 0] = a.x; sA[o + 1] = a.y; sA[o + 2] = a.z; sA[o + 3] = a.w;
        int b, i, j, m; decodePos((int)p, b, i, j, m);
        long pT = ((long)(b * nN + j) * nN + i) * nN + m;
        float4 t4 = *(const float4*)(t + pT * nC + cq * 4);
        sB[o + 0] = t4.x; sB[o + 1] = t4.y; sB[o + 2] = t4.z; sB[o + 3] = t4.w;
    }
    __syncthreads();
    const int pt = tid >> 3, dq = tid & 7;
    const int p0 = pt * 4, d0 = dq * 2;
    float wc[32][2], acc[4][2];
    #pragma unroll
    for (int l = 0; l < 4; ++l) { acc[l][0] = 0.f; acc[l][1] = 0.f; }

    auto loadW = [&](const float* Wp) {
        #pragma unroll
        for (int c2 = 0; c2 < 32; ++c2) {
            float2 q2 = *(const float2*)(Wp + c2 * 16 + d0);
            wc[c2][0] = q2.x; wc[c2][1] = q2.y;
        }
    };
    auto sweep = [&](const float* sp) {           // b64: 2 channels / inst
        #pragma unroll
        for (int cp = 0; cp < 16; ++cp) {
            float2 t0 = *(const float2*)(sp + (p0 + 0) * 34 + cp * 2);
            float2 t1 = *(const float2*)(sp + (p0 + 1) * 34 + cp * 2);
            float2 t2 = *(const float2*)(sp + (p0 + 2) * 34 + cp * 2);
            float2 t3 = *(const float2*)(sp + (p0 + 3) * 34 + cp * 2);
            const int c0 = cp * 2, c1 = cp * 2 + 1;
            acc[0][0] = fmaf(t0.x, wc[c0][0], acc[0][0]); acc[0][1] = fmaf(t0.x, wc[c0][1], acc[0][1]);
            acc[1][0] = fmaf(t1.x, wc[c0][0], acc[1][0]); acc[1][1] = fmaf(t1.x, wc[c0][1], acc[1][1]);
            acc[2][0] = fmaf(t2.x, wc[c0][0], acc[2][0]); acc[2][1] = fmaf(t2.x, wc[c0][1], acc[2][1]);
            acc[3][0] = fmaf(t3.x, wc[c0][0], acc[3][0]); acc[3][1] = fmaf(t3.x, wc[c0][1], acc[3][1]);
            acc[0][0] = fmaf(t0.y, wc[c1][0], acc[0][0]); acc[0][1] = fmaf(t0.y, wc[c1][1], acc[0][1]);
            acc[1][0] = fmaf(t1.y, wc[c1][0], acc[1][0]); acc[1][1] = fmaf(t1.y, wc[c1][1], acc[1][1]);
            acc[2][0] = fmaf(t2.y, wc[c1][0], acc[2][0]); acc[2][1] = fmaf(t2.y, wc[c1][1], acc[2][1]);
            acc[3][0] = fmaf(t3.y, wc[c1][0], acc[3][0]); acc[3][1] = fmaf(t3.y, wc[c1][1], acc[3][1]);
        }
    };

    loadW(W0); sweep(sA);
    loadW(W1); sweep(sB);

    #pragma unroll
    for (int l = 0; l < 4; ++l) {
        int p = (int)base + p0 + l;
        int b, i, j, m; decodePos(p, b, i, j, m);
        float2 d2 = *(const float2*)(drp + (size_t)((b * nN + i) * nN + m) * 16 + d0);
        float2 cc2 = *(const float2*)(ccp + (size_t)((b * nN + j) * nN + m) * 16 + d0);
        float2 tb2 = *(const float2*)(tbp + (size_t)(b * nN + m) * 16 + d0);
        float mk = vm[b * nN + i] * vm[b * nN + j] * vm[b * nN + m];
        float2 o2;
        o2.x = (acc[l][0] + d2.x + cc2.x + tb2.x) * mk;
        o2.y = (acc[l][1] + d2.y + cc2.y + tb2.y) * mk;
        *(float2*)(out + (size_t)p * 16 + d0) = o2;
    }
}

} // anonymous namespace

// ---------------------------------------------------------------------------
extern "C" void kernel_launch(void* const* d_in, const int* in_sizes, int n_in,
                              void* d_out, int out_size, void* d_ws, size_t ws_size,
                              hipStream_t stream)
{
    (void)in_sizes; (void)n_in; (void)out_size; (void)ws_size;
    const float* x    = (const float*)d_in[0];
    const void*  mask = d_in[1];
    const float* bW0  = (const float*)d_in[2];
    const float* bb0  = (const float*)d_in[3];
    const float* lvW0 = (const float*)d_in[4];
    const float* lvb0 = (const float*)d_in[5];
    const float* lwW0 = (const float*)d_in[6];
    const float* lwb0 = (const float*)d_in[7];
    const float* loW0 = (const float*)d_in[8];
    const float* lob0 = (const float*)d_in[9];
    const float* bW1  = (const float*)d_in[10];
    const float* bb1  = (const float*)d_in[11];
    const float* lvW1 = (const float*)d_in[12];
    const float* lvb1 = (const float*)d_in[13];
    const float* lwW1 = (const float*)d_in[14];
    const float* lwb1 = (const float*)d_in[15];
    const float* loW1 = (const float*)d_in[16];
    const float* lob1 = (const float*)d_in[17];
    const float* fW   = (const float*)d_in[18];
    const float* fb   = (const float*)d_in[19];

    float* ws  = (float*)d_ws;
    float* t     = ws;                          // 14155776
    float* v     = ws + 14155776L;
    float* w     = ws + 28311552L;
    float* rows2 = ws + 42467328L;              // 2 * 294912
    float* cols2 = rows2 + 2 * 294912;          // 2 * 294912
    float* diag  = cols2 + 2 * 294912;          // 294912
    float* tot4  = diag + 294912;               // 4 * 6144
    float* drv   = tot4 + 4 * 6144;             // 294912
    float* ccv   = drv + 294912;                // 294912
    float* tbv   = ccv + 294912;                // 6144
    float* drw   = tbv + 6144;                  // 294912
    float* ccw   = drw + 294912;                // 294912
    float* tbw   = ccw + 294912;                // 6144
    float* cW    = tbw + 6144;                  // 4 * 6144 composed basic-W
    float* cb    = cW + 4 * 6144;               // 4 * 32 composed biases
    float* cWs   = cb + 128;                    // 2 * 1024 summed layer-0
    float* S     = cWs + 2048;                  // 128
    float* vm    = S + 128;                     // 192
    float* out   = (float*)d_out;

    k_prep<<<1, 256, 0, stream>>>(x, mask, vm, S);
    k_compose<<<4, 256, 0, stream>>>(bW0, bb0, lvW0, lwW0, bW1, bb1, lvW1, lwW1, cW, cb, cWs);

    // ---- layer 0 ----
    k_mix0<<<36, 256, 0, stream>>>(x, S, cW + 0,    cb + 0,  drv, ccv, tbv);
    k_mix0<<<36, 256, 0, stream>>>(x, S, cW + 6144, cb + 32, drw, ccw, tbw);
    k_vw<0><<<3456, 256, 0, stream>>>(x, vm, drv, ccv, tbv, drw, ccw, tbw,
                                      cWs + 0,   cWs + 0,     // (W0+W1)@Wv
                                      cWs + 1024, cWs + 1024, // (W0+W1)@Ww
                                      lvb0, lwb0, v, w);
    k_z<<<768, 256, 0, stream>>>(v, w, loW0, lob0, vm, t, rows2, cols2, diag, tot4);

    // ---- layer 1 ----
    k_mix<32><<<36, 256, 0, stream>>>(diag, rows2, cols2, tot4, cW + 12288, cb + 64, drv, ccv, tbv);
    k_mix<32><<<36, 256, 0, stream>>>(diag, rows2, cols2, tot4, cW + 18432, cb + 96, drw, ccw, tbw);
    k_vw<1><<<3456, 256, 0, stream>>>(t, vm, drv, ccv, tbv, drw, ccw, tbw,
                                      cW + 12288, cW + 13312,  // W0@Wv, W1@Wv
                                      cW + 18432, cW + 19456,  // W0@Ww, W1@Ww
                                      lvb1, lwb1, v, w);
    k_z<<<768, 256, 0, stream>>>(v, w, loW1, lob1, vm, t, rows2, cols2, diag, tot4);

    // ---- final snconv2 (uncomposed, 16ch) ----
    k_mix<16><<<36, 256, 0, stream>>>(diag, rows2, cols2, tot4, fW, fb, drv, ccv, tbv);
    k_final<<<3456, 256, 0, stream>>>(t, vm, drv, ccv, tbv, fW, fW + 512, out);
}

// Round 3
// 547.789 us; speedup vs baseline: 1.5711x; 1.5711x over previous
//
#include <hip/hip_runtime.h>
#include <cstdint>

// ---------------------------------------------------------------------------
// SnLocalDecoder: B=4, n=48, C=32. Round-12 = R11 dual-accumulator k_vw with
//  the two proven failure modes fixed:
//   (a) R11 passed accumulators to the epilogue as float(*)[4] -> address
//       taken -> scratch (WRITE 110->761MB). Epilogues are now inline blocks
//       naming accv/accw directly.
//   (b) weights live in LDS (staged behind the same single barrier), not in a
//       wc[32][4] register cache (R10: 248 VGPR) nor streamed from global
//       (R11: hoisting pressure). Sweeps read weights via ds_read_b128,
//       broadcast across position groups, conflict-free.
//  No launch_bounds VGPR cap. sched_barrier(0) fences keep epilogue loads out
//  of the sweeps. k_z / k_mix / k_final / composition unchanged from R11.
// ---------------------------------------------------------------------------

namespace {

constexpr int nB = 4, nN = 48, nC = 32;
constexpr int SJ_ = nN * nC;            // 1536
constexpr int SI_ = nN * SJ_;           // 73728
constexpr long SB_ = (long)nN * SI_;    // 3538944
constexpr int RP_ = 294912;             // rows-partial stride (2 partials)
constexpr int CP_ = 294912;             // cols-partial stride (2 partials)
constexpr int TP_ = 6144;               // tot-partial stride  (4 partials)

__device__ __forceinline__ void decodePos(int p, int& b, int& i, int& j, int& m) {
    m = p % nN; int r = p / nN;
    j = r % nN; r /= nN;
    i = r % nN; b = r / nN;
}

// ---------------------------------------------------------------------------
__global__ __launch_bounds__(256) void k_prep(const float* __restrict__ x,
                                              const void* __restrict__ maskp,
                                              float* __restrict__ vm,
                                              float* __restrict__ S)
{
    __shared__ float vmL[nB * nN];
    const int tid = threadIdx.x;
    const unsigned int w0 = *(const unsigned int*)maskp;
    const bool is_byte = (w0 == 0x01010101u);   // bool-byte layout
    if (tid < nB * nN) {
        int b = tid / nN, i = tid % nN;
        long idx = ((long)(b * nN + i) * nN + i) * nN + i;   // mask[b,i,i,i]
        int bit;
        if (is_byte) bit = (((const unsigned char*)maskp)[idx] != 0);
        else         bit = (((const int*)maskp)[idx] != 0);
        float f = bit ? 1.f : 0.f;
        vm[tid] = f; vmL[tid] = f;
    }
    __syncthreads();
    if (tid < nB * nC) {
        int b = tid >> 5, c = tid & 31;
        float s = 0.f;
        for (int j = 0; j < nN; ++j) s += x[(b * nN + j) * nC + c] * vmL[b * nN + j];
        S[tid] = s;
    }
}

// ---------------------------------------------------------------------------
// Compose basic-conv weights with Wv / Ww:  cW[blk][k][c][d] = Wb[k]@Wr,
// cb[blk][d] = b@Wr.  blk: 0=L0v 1=L0w 2=L1v 3=L1w.
// Also cWs[blk][c][d] = (Wb[0]+Wb[1])@Wr for blk 0,1 (layer-0 symmetric t).
__global__ __launch_bounds__(256) void k_compose(
    const float* __restrict__ Wb0, const float* __restrict__ bb0,
    const float* __restrict__ Wv0, const float* __restrict__ Ww0,
    const float* __restrict__ Wb1, const float* __restrict__ bb1,
    const float* __restrict__ Wv1, const float* __restrict__ Ww1,
    float* __restrict__ cW, float* __restrict__ cb, float* __restrict__ cWs)
{
    const int blk = blockIdx.x;              // 0..3
    const float* Wb = (blk < 2) ? Wb0 : Wb1;
    const float* bb = (blk < 2) ? bb0 : bb1;
    const float* Wr = (blk == 0) ? Wv0 : (blk == 1) ? Ww0 : (blk == 2) ? Wv1 : Ww1;
    __shared__ float Ws[1024];
    const int tid = threadIdx.x;
    for (int q = tid; q < 1024; q += 256) Ws[q] = Wr[q];
    __syncthreads();
    for (int q = tid; q < 6144; q += 256) {
        const int d = q & 31;
        const float* row = Wb + (q >> 5) * 32;   // (k*32+c2) row, stride 32
        float s = 0.f;
        #pragma unroll
        for (int e = 0; e < 32; ++e) s = fmaf(row[e], Ws[e * 32 + d], s);
        cW[blk * 6144 + q] = s;
    }
    if (blk < 2) {
        for (int q = tid; q < 1024; q += 256) {
            const int d = q & 31; const int c = q >> 5;
            const float* r0 = Wb + c * 32;           // k=0 row
            const float* r1 = Wb + 1024 + c * 32;    // k=1 row
            float s = 0.f;
            #pragma unroll
            for (int e = 0; e < 32; ++e) s = fmaf(r0[e] + r1[e], Ws[e * 32 + d], s);
            cWs[blk * 1024 + q] = s;
        }
    }
    if (tid < 32) {
        float s = 0.f;
        #pragma unroll
        for (int e = 0; e < 32; ++e) s = fmaf(bb[e], Ws[e * 32 + tid], s);
        cb[blk * 32 + tid] = s;
    }
}

// ---------------------------------------------------------------------------
// Layer-0 small snconv2 terms, closed form from x and S.
__global__ __launch_bounds__(256) void k_mix0(
    const float* __restrict__ x, const float* __restrict__ S,
    const float* __restrict__ Wb, const float* __restrict__ bias,
    float* __restrict__ drp, float* __restrict__ ccp, float* __restrict__ tbp)
{
    __shared__ float W2s[1024], W3s[1024], W4s[1024], W5s[1024], bs[32];
    const int tid = threadIdx.x;
    for (int q = tid; q < 1024; q += 256) {
        W2s[q] = Wb[2048 + q]; W3s[q] = Wb[3072 + q];
        W4s[q] = Wb[4096 + q]; W5s[q] = Wb[5120 + q];
    }
    if (tid < 32) bs[tid] = bias[tid];
    __syncthreads();
    const int id = blockIdx.x * 256 + tid;        // (b*48+i)*48+m
    const int m = id % nN; int r = id / nN; const int i = r % nN; const int b = r / nN;
    float odr[32], occ[32];
    #pragma unroll
    for (int d = 0; d < 32; ++d) { odr[d] = 0.f; occ[d] = 0.f; }
    for (int c2 = 0; c2 < 32; ++c2) {
        float xi = x[(b * nN + i) * nC + c2];
        float xm = x[(b * nN + m) * nC + c2];
        float sc = S[b * nC + c2];
        float A = xi * xi * xm;
        float R = xi * xm * sc * (1.f / nN);
        #pragma unroll
        for (int d = 0; d < 32; ++d) {
            odr[d] = fmaf(A, W2s[c2 * 32 + d], fmaf(R, W3s[c2 * 32 + d], odr[d]));
            occ[d] = fmaf(R, W4s[c2 * 32 + d], occ[d]);
        }
    }
    #pragma unroll
    for (int d = 0; d < 32; d += 4) {
        *(float4*)(drp + (size_t)id * 32 + d) = make_float4(odr[d], odr[d+1], odr[d+2], odr[d+3]);
        *(float4*)(ccp + (size_t)id * 32 + d) = make_float4(occ[d], occ[d+1], occ[d+2], occ[d+3]);
    }
    if (i == 0) {
        float ot[32];
        #pragma unroll
        for (int d = 0; d < 32; ++d) ot[d] = bs[d];
        for (int c2 = 0; c2 < 32; ++c2) {
            float xm = x[(b * nN + m) * nC + c2];
            float sc = S[b * nC + c2];
            float Tc = xm * sc * sc * (1.f / (nN * nN));
            #pragma unroll
            for (int d = 0; d < 32; ++d) ot[d] = fmaf(Tc, W5s[c2 * 32 + d], ot[d]);
        }
        for (int d = 0; d < 32; d += 4)
            *(float4*)(tbp + (size_t)(b * nN + m) * 32 + d) = make_float4(ot[d], ot[d+1], ot[d+2], ot[d+3]);
    }
}

// ---------------------------------------------------------------------------
// Small snconv2 terms from k_z's partial reductions (2 rows, 2 cols, 4 tot).
template <int DOUT>
__global__ __launch_bounds__(256) void k_mix(
    const float* __restrict__ dgp, const float* __restrict__ rw2,
    const float* __restrict__ cl2, const float* __restrict__ tt4,
    const float* __restrict__ Wb, const float* __restrict__ bias,
    float* __restrict__ drp, float* __restrict__ ccp, float* __restrict__ tbp)
{
    __shared__ float W2s[32 * DOUT], W3s[32 * DOUT], W4s[32 * DOUT], W5s[32 * DOUT], bs[DOUT];
    const int tid = threadIdx.x;
    for (int q = tid; q < 32 * DOUT; q += 256) {
        W2s[q] = Wb[2 * 32 * DOUT + q]; W3s[q] = Wb[3 * 32 * DOUT + q];
        W4s[q] = Wb[4 * 32 * DOUT + q]; W5s[q] = Wb[5 * 32 * DOUT + q];
    }
    if (tid < DOUT) bs[tid] = bias[tid];
    __syncthreads();
    const int id = blockIdx.x * 256 + tid;
    const int m = id % nN; int r = id / nN; const int i = r % nN; const int b = r / nN;
    float odr[DOUT], occ[DOUT];
    #pragma unroll
    for (int d = 0; d < DOUT; ++d) { odr[d] = 0.f; occ[d] = 0.f; }
    for (int c2 = 0; c2 < 32; ++c2) {
        size_t q = (size_t)id * 32 + c2;
        float dg = dgp[q];
        float rw = (rw2[q] + rw2[q + RP_]) * (1.f / nN);
        float cl = (cl2[q] + cl2[q + CP_]) * (1.f / nN);
        #pragma unroll
        for (int d = 0; d < DOUT; ++d) {
            odr[d] = fmaf(dg, W2s[c2 * DOUT + d], fmaf(rw, W3s[c2 * DOUT + d], odr[d]));
            occ[d] = fmaf(cl, W4s[c2 * DOUT + d], occ[d]);
        }
    }
    #pragma unroll
    for (int d = 0; d < DOUT; d += 4) {
        *(float4*)(drp + (size_t)id * DOUT + d) = make_float4(odr[d], odr[d+1], odr[d+2], odr[d+3]);
        *(float4*)(ccp + (size_t)id * DOUT + d) = make_float4(occ[d], occ[d+1], occ[d+2], occ[d+3]);
    }
    if (i == 0) {
        float ot[DOUT];
        #pragma unroll
        for (int d = 0; d < DOUT; ++d) ot[d] = bs[d];
        for (int c2 = 0; c2 < 32; ++c2) {
            size_t q = (size_t)(b * nN + m) * 32 + c2;
            float tv = (tt4[q] + tt4[q + TP_] + tt4[q + 2 * TP_] + tt4[q + 3 * TP_])
                       * (1.f / (nN * nN));
            #pragma unroll
            for (int d = 0; d < DOUT; ++d) ot[d] = fmaf(tv, W5s[c2 * DOUT + d], ot[d]);
        }
        for (int d = 0; d < DOUT; d += 4)
            *(float4*)(tbp + (size_t)(b * nN + m) * DOUT + d) = make_float4(ot[d], ot[d+1], ot[d+2], ot[d+3]);
    }
}

// ---------------------------------------------------------------------------
// Composed-weight v/w producer, dual-accumulator, LDS weights:
//   v = mk * ( t@(W0@Wv) + tT@(W1@Wv) + drv + ccv + tbv ) + bv    (w alike)
// One barrier. Each LDS t-value is read once and FMA'd into BOTH accv and
// accw; weights come from LDS (b128 reads, broadcast over position groups).
// Wv2 points at contiguous [WAv|WBv] (MODE0: [Wv'|Ww']); Ww2 at [WAw|WBw].
#define FMA4(ar, tv, w4)                       \
    ar[0] = fmaf(tv, w4.x, ar[0]);             \
    ar[1] = fmaf(tv, w4.y, ar[1]);             \
    ar[2] = fmaf(tv, w4.z, ar[2]);             \
    ar[3] = fmaf(tv, w4.w, ar[3]);

template <int MODE>
__global__ __launch_bounds__(256) void k_vw(
    const float* __restrict__ src, const float* __restrict__ vm,
    const float* __restrict__ drv, const float* __restrict__ ccv, const float* __restrict__ tbv,
    const float* __restrict__ drw, const float* __restrict__ ccw, const float* __restrict__ tbw,
    const float* __restrict__ Wv2, const float* __restrict__ Ww2,
    const float* __restrict__ bv, const float* __restrict__ bw,
    float* __restrict__ vout, float* __restrict__ wout)
{
    __shared__ float sA[128 * 34];
    __shared__ float sB[(MODE == 0) ? 4 : 128 * 34];
    __shared__ float wL[(MODE == 0) ? 2048 : 4096];
    const int tid = threadIdx.x;
    const long base = (long)blockIdx.x * 128;

    // ---- weights -> LDS (behind the same single barrier) ----
    {
        float4* wl4 = (float4*)wL;
        if (MODE == 0) {
            for (int q = tid; q < 512; q += 256) wl4[q] = ((const float4*)Wv2)[q];
        } else {
            for (int q = tid; q < 512; q += 256) wl4[q] = ((const float4*)Wv2)[q];
            for (int q = tid; q < 512; q += 256) wl4[512 + q] = ((const float4*)Ww2)[q];
        }
    }
    // ---- t (and tT) -> LDS ----
    if (MODE == 0) {
        for (int rep = 0; rep < 4; ++rep) {
            int q = rep * 256 + tid; int pl = q >> 3, cq = q & 7;
            int p = (int)base + pl;
            int b, i, j, m; decodePos(p, b, i, j, m);
            float4 xi = *(const float4*)(src + (size_t)(b * nN + i) * nC + cq * 4);
            float4 xj = *(const float4*)(src + (size_t)(b * nN + j) * nC + cq * 4);
            float4 xm = *(const float4*)(src + (size_t)(b * nN + m) * nC + cq * 4);
            int o = pl * 34 + cq * 4;
            sA[o + 0] = xi.x * xj.x * xm.x;
            sA[o + 1] = xi.y * xj.y * xm.y;
            sA[o + 2] = xi.z * xj.z * xm.z;
            sA[o + 3] = xi.w * xj.w * xm.w;
        }
    } else {
        for (int rep = 0; rep < 4; ++rep) {
            int q = rep * 256 + tid; int pl = q >> 3, cq = q & 7;
            long p = base + pl;
            float4 a = *(const float4*)(src + p * nC + cq * 4);
            int o = pl * 34 + cq * 4;
            sA[o + 0] = a.x; sA[o + 1] = a.y; sA[o + 2] = a.z; sA[o + 3] = a.w;
            int b, i, j, m; decodePos((int)p, b, i, j, m);
            long pT = ((long)(b * nN + j) * nN + i) * nN + m;
            float4 t4 = *(const float4*)(src + pT * nC + cq * 4);
            sB[o + 0] = t4.x; sB[o + 1] = t4.y; sB[o + 2] = t4.z; sB[o + 3] = t4.w;
        }
    }
    __syncthreads();                         // the ONLY barrier

    const int pt = tid >> 3, dq = tid & 7;
    const int p0 = pt * 4, d0 = dq * 4;
    float accv[4][4], accw[4][4];
    #pragma unroll
    for (int l = 0; l < 4; ++l)
        #pragma unroll
        for (int d = 0; d < 4; ++d) { accv[l][d] = 0.f; accw[l][d] = 0.f; }

    auto sweep_dual = [&](const float* sp, const float* wv_, const float* ww_) {
        #pragma unroll
        for (int cp = 0; cp < 16; ++cp) {
            float2 t0 = *(const float2*)(sp + (p0 + 0) * 34 + cp * 2);
            float2 t1 = *(const float2*)(sp + (p0 + 1) * 34 + cp * 2);
            float2 t2 = *(const float2*)(sp + (p0 + 2) * 34 + cp * 2);
            float2 t3 = *(const float2*)(sp + (p0 + 3) * 34 + cp * 2);
            const int c0 = cp * 2, c1 = cp * 2 + 1;
            float4 wv0 = *(const float4*)(wv_ + c0 * nC + d0);
            float4 wv1 = *(const float4*)(wv_ + c1 * nC + d0);
            float4 ww0 = *(const float4*)(ww_ + c0 * nC + d0);
            float4 ww1 = *(const float4*)(ww_ + c1 * nC + d0);
            FMA4(accv[0], t0.x, wv0); FMA4(accv[1], t1.x, wv0);
            FMA4(accv[2], t2.x, wv0); FMA4(accv[3], t3.x, wv0);
            FMA4(accv[0], t0.y, wv1); FMA4(accv[1], t1.y, wv1);
            FMA4(accv[2], t2.y, wv1); FMA4(accv[3], t3.y, wv1);
            FMA4(accw[0], t0.x, ww0); FMA4(accw[1], t1.x, ww0);
            FMA4(accw[2], t2.x, ww0); FMA4(accw[3], t3.x, ww0);
            FMA4(accw[0], t0.y, ww1); FMA4(accw[1], t1.y, ww1);
            FMA4(accw[2], t2.y, ww1); FMA4(accw[3], t3.y, ww1);
        }
    };

    if (MODE == 0) {
        sweep_dual(sA, wL, wL + 1024);       // weights pre-summed (W0+W1)@Wr
    } else {
        sweep_dual(sA, wL, wL + 2048);       // t  @ WAv / WAw
        sweep_dual(sB, wL + 1024, wL + 3072);// tT @ WBv / WBw
    }

    __builtin_amdgcn_sched_barrier(0);       // keep epilogue loads out of sweeps
    {   // ---- epilogue v (accv by name: no address taken, no scratch) ----
        float4 b4 = *(const float4*)(bv + d0);
        #pragma unroll
        for (int l = 0; l < 4; ++l) {
            int p = (int)base + p0 + l;
            int b, i, j, m; decodePos(p, b, i, j, m);
            float4 d4 = *(const float4*)(drv + (size_t)((b * nN + i) * nN + m) * nC + d0);
            float4 c4 = *(const float4*)(ccv + (size_t)((b * nN + j) * nN + m) * nC + d0);
            float4 t4 = *(const float4*)(tbv + (size_t)(b * nN + m) * nC + d0);
            float mk = vm[b * nN + i] * vm[b * nN + j] * vm[b * nN + m];
            float4 o4;
            o4.x = (accv[l][0] + d4.x + c4.x + t4.x) * mk + b4.x;
            o4.y = (accv[l][1] + d4.y + c4.y + t4.y) * mk + b4.y;
            o4.z = (accv[l][2] + d4.z + c4.z + t4.z) * mk + b4.z;
            o4.w = (accv[l][3] + d4.w + c4.w + t4.w) * mk + b4.w;
            *(float4*)(vout + (size_t)(base + p0 + l) * nC + d0) = o4;
        }
    }
    __builtin_amdgcn_sched_barrier(0);       // keep w-epilogue from fusing into v
    {   // ---- epilogue w ----
        float4 b4 = *(const float4*)(bw + d0);
        #pragma unroll
        for (int l = 0; l < 4; ++l) {
            int p = (int)base + p0 + l;
            int b, i, j, m; decodePos(p, b, i, j, m);
            float4 d4 = *(const float4*)(drw + (size_t)((b * nN + i) * nN + m) * nC + d0);
            float4 c4 = *(const float4*)(ccw + (size_t)((b * nN + j) * nN + m) * nC + d0);
            float4 t4 = *(const float4*)(tbw + (size_t)(b * nN + m) * nC + d0);
            float mk = vm[b * nN + i] * vm[b * nN + j] * vm[b * nN + m];
            float4 o4;
            o4.x = (accw[l][0] + d4.x + c4.x + t4.x) * mk + b4.x;
            o4.y = (accw[l][1] + d4.y + c4.y + t4.y) * mk + b4.y;
            o4.z = (accw[l][2] + d4.z + c4.z + t4.z) * mk + b4.z;
            o4.w = (accw[l][3] + d4.w + c4.w + t4.w) * mk + b4.w;
            *(float4*)(wout + (size_t)(base + p0 + l) * nC + d0) = o4;
        }
    }
}

// ---------------------------------------------------------------------------
// z = V*W/n per (b,m); o-mix + relu + mask -> t; fused rows/cols/diag/tot
// partial reductions (no atomics). Tile 24i x 24j x 32c; 768 blocks.
__global__ __launch_bounds__(256, 3) void k_z(
    const float* __restrict__ v, const float* __restrict__ w,
    const float* __restrict__ Wo, const float* __restrict__ bo,
    const float* __restrict__ vm, float* __restrict__ tout,
    float* __restrict__ rows2, float* __restrict__ cols2,
    float* __restrict__ diag_, float* __restrict__ tot4)
{
    __shared__ float lds[12912];           // 51648 B -> 3 blocks/CU
    float* Vt = lds;                       // [kk][c][i]: kk*807 + c*25 + i
    float* Wt = lds + 6456;
    constexpr int ZS = 34;                 // z/out row stride (per position)
    constexpr int ZWO = 9792;              // Wo area
    constexpr int TOT0 = 10816;            // tot scratch [8][32]
    const int tid = threadIdx.x;
    const int blk = blockIdx.x;
    const int tl = blk & 3; const int bm = blk >> 2;
    const int it = tl >> 1, jt = tl & 1;
    const int b = bm / nN, m = bm % nN;
    const int c = tid & 31;
    const int g = tid >> 5;
    const int i3 = g >> 1, j2 = g & 1;     // i3 wave-uniform
    const int il0 = i3 * 6, jl0 = j2 * 12;
    const size_t posbase = (size_t)b * SB_ + (size_t)m * nC;

    float acc[6][12];
    #pragma unroll
    for (int l = 0; l < 6; ++l)
        #pragma unroll
        for (int u = 0; u < 12; ++u) acc[l][u] = 0.f;

    for (int kc = 0; kc < 6; ++kc) {
        if (kc) __syncthreads();
        #pragma unroll
        for (int rr = 0; rr < 6; ++rr) {          // V: 24i x 8k x 32c
            int q = rr * 256 + tid; int pos = q >> 3, cq = q & 7;
            int ii = pos >> 3, kk = pos & 7;
            float4 a = *(const float4*)(v + posbase + (size_t)(it * 24 + ii) * SI_
                                          + (size_t)(kc * 8 + kk) * SJ_ + cq * 4);
            float* dst = Vt + kk * 807 + (cq * 4) * 25 + ii;
            dst[0] = a.x; dst[25] = a.y; dst[50] = a.z; dst[75] = a.w;
        }
        #pragma unroll
        for (int rr = 0; rr < 6; ++rr) {          // W: 8k x 24j x 32c
            int q = rr * 256 + tid; int pos = q >> 3, cq = q & 7;
            int kk = pos / 24, jj = pos - kk * 24;
            float4 a = *(const float4*)(w + posbase + (size_t)(kc * 8 + kk) * SI_
                                          + (size_t)(jt * 24 + jj) * SJ_ + cq * 4);
            float* dst = Wt + kk * 807 + (cq * 4) * 25 + jj;
            dst[0] = a.x; dst[25] = a.y; dst[50] = a.z; dst[75] = a.w;
        }
        __syncthreads();
        #pragma unroll
        for (int kk = 0; kk < 8; ++kk) {
            float vf[6], wf[12];
            #pragma unroll
            for (int l = 0; l < 6; ++l) vf[l] = Vt[kk * 807 + c * 25 + il0 + l];
            #pragma unroll
            for (int u = 0; u < 12; ++u) wf[u] = Wt[kk * 807 + c * 25 + jl0 + u];
            #pragma unroll
            for (int l = 0; l < 6; ++l)
                #pragma unroll
                for (int u = 0; u < 12; ++u)
                    acc[l][u] = fmaf(vf[l], wf[u], acc[l][u]);
        }
    }
    __syncthreads();                               // staging area now reusable

    #pragma unroll
    for (int e = 0; e < 4; ++e)                    // Wo * (1/48)
        lds[ZWO + e * 256 + tid] = Wo[e * 256 + tid] * (1.f / nN);

    const int ptE = tid >> 3, dqE = tid & 7, d0 = dqE * 4;
    const float4 b4 = *(const float4*)(bo + d0);
    const float vmm = vm[b * nN + m];
    float colacc[3] = {0.f, 0.f, 0.f};
    float totacc = 0.f;

    for (int h = 0; h < 2; ++h) {
        if (h) __syncthreads();                    // protect h=0 reduction reads
        if ((i3 >> 1) == h) {                      // write this half's z
            int r0 = il0 - 12 * h;                 // 0 or 6
            #pragma unroll
            for (int l = 0; l < 6; ++l)
                #pragma unroll
                for (int u = 0; u < 12; ++u)
                    lds[((r0 + l) * 24 + jl0 + u) * ZS + c] = acc[l][u];
        }
        __syncthreads();                           // z + wo visible

        float oac[9][4];
        #pragma unroll
        for (int u = 0; u < 9; ++u)
            #pragma unroll
            for (int d = 0; d < 4; ++d) oac[u][d] = 0.f;
        #pragma unroll
        for (int c2 = 0; c2 < 32; ++c2) {
            float4 wo4 = *(const float4*)(lds + ZWO + c2 * 32 + d0);
            float zv[9];
            #pragma unroll
            for (int u = 0; u < 9; ++u) zv[u] = lds[(ptE * 9 + u) * ZS + c2];
            #pragma unroll
            for (int u = 0; u < 9; ++u) {
                oac[u][0] = fmaf(zv[u], wo4.x, oac[u][0]);
                oac[u][1] = fmaf(zv[u], wo4.y, oac[u][1]);
                oac[u][2] = fmaf(zv[u], wo4.z, oac[u][2]);
                oac[u][3] = fmaf(zv[u], wo4.w, oac[u][3]);
            }
        }
        __syncthreads();                           // all z reads done

        #pragma unroll
        for (int u = 0; u < 9; ++u) {
            int p = ptE * 9 + u;
            int rl = p / 24, jl = p - rl * 24;
            int gi = it * 24 + 12 * h + rl, gj = jt * 24 + jl;
            float mk = vm[b * nN + gi] * vm[b * nN + gj] * vmm;
            float4 o4;
            o4.x = fmaxf(oac[u][0] + b4.x, 0.f) * mk;
            o4.y = fmaxf(oac[u][1] + b4.y, 0.f) * mk;
            o4.z = fmaxf(oac[u][2] + b4.z, 0.f) * mk;
            o4.w = fmaxf(oac[u][3] + b4.w, 0.f) * mk;
            *(float4*)(tout + posbase + (size_t)gi * SI_ + (size_t)gj * SJ_ + d0) = o4;
            *(float2*)(lds + p * ZS + d0) = make_float2(o4.x, o4.y);
            *(float2*)(lds + p * ZS + d0 + 2) = make_float2(o4.z, o4.w);
        }
        __syncthreads();                           // out tile visible in LDS

        for (int rd = 0; rd < 2; ++rd) {
            int task = rd * 256 + tid;
            if (task < 384) {
                int i_r = task >> 5, c_r = task & 31;
                float rsum = 0.f;
                #pragma unroll
                for (int jl = 0; jl < 24; ++jl) rsum += lds[(i_r * 24 + jl) * ZS + c_r];
                int gi = it * 24 + 12 * h + i_r;
                rows2[(size_t)jt * RP_ + ((size_t)(b * nN + gi) * nN + m) * nC + c_r] = rsum;
                totacc += rsum;
                if (it == jt)
                    diag_[((size_t)(b * nN + gi) * nN + m) * nC + c_r] =
                        lds[(i_r * 24 + (12 * h + i_r)) * ZS + c_r];
            }
        }
        #pragma unroll
        for (int rr = 0; rr < 3; ++rr) {
            int task = rr * 256 + tid;
            int jl = task >> 5, c_c = task & 31;
            float csum = 0.f;
            #pragma unroll
            for (int il = 0; il < 12; ++il) csum += lds[(il * 24 + jl) * ZS + c_c];
            colacc[rr] += csum;
        }
    }

    #pragma unroll
    for (int rr = 0; rr < 3; ++rr) {
        int task = rr * 256 + tid;
        int jl = task >> 5, c_c = task & 31;
        cols2[(size_t)it * CP_ + ((size_t)(b * nN + jt * 24 + jl) * nN + m) * nC + c_c] = colacc[rr];
    }
    lds[TOT0 + g * 32 + c] = totacc;
    __syncthreads();
    if (tid < 32) {
        float s = 0.f;
        #pragma unroll
        for (int gg = 0; gg < 8; ++gg) s += lds[TOT0 + gg * 32 + tid];
        tot4[(size_t)(it * 2 + jt) * TP_ + (size_t)(b * nN + m) * nC + tid] = s;
    }
}

// ---------------------------------------------------------------------------
// Final snconv2 (C_out = 16), masked, direct to d_out. b64 sweeps.
__global__ __launch_bounds__(256) void k_final(
    const float* __restrict__ t, const float* __restrict__ vm,
    const float* __restrict__ drp, const float* __restrict__ ccp, const float* __restrict__ tbp,
    const float* __restrict__ W0, const float* __restrict__ W1,
    float* __restrict__ out)
{
    __shared__ float sA[128 * 34], sB[128 * 34];
    const int tid = threadIdx.x;
    const long base = (long)blockIdx.x * 128;
    for (int rep = 0; rep < 4; ++rep) {
        int q = rep * 256 + tid; int pl = q >> 3, cq = q & 7;
        long p = base + pl;
        float4 a = *(const float4*)(t + p * nC + cq * 4);
        int o = pl * 34 + cq * 4;
        sA[o + 0] = a.x; sA[o + 1] = a.y; sA[o + 2] = a.z; sA[o + 3] = a.w;
        int b, i, j, m; decodePos((int)p, b, i, j, m);
        long pT = ((long)(b * nN + j) * nN + i) * nN + m;
        float4 t4 = *(const float4*)(t + pT * nC + cq * 4);
        sB[o + 0] = t4.x; sB[o + 1] = t4.y; sB[o + 2] = t4.z; sB[o + 3] = t4.w;
    }
    __syncthreads();
    const int pt = tid >> 3, dq = tid & 7;
    const int p0 = pt * 4, d0 = dq * 2;
    float wc[32][2], acc[4][2];
    #pragma unroll
    for (int l = 0; l < 4; ++l) { acc[l][0] = 0.f; acc[l][1] = 0.f; }

    auto loadW = [&](const float* Wp) {
        #pragma unroll
        for (int c2 = 0; c2 < 32; ++c2) {
            float2 q2 = *(const float2*)(Wp + c2 * 16 + d0);
            wc[c2][0] = q2.x; wc[c2][1] = q2.y;
        }
    };
    auto sweep = [&](const float* sp) {           // b64: 2 channels / inst
        #pragma unroll
        for (int cp = 0; cp < 16; ++cp) {
            float2 t0 = *(const float2*)(sp + (p0 + 0) * 34 + cp * 2);
            float2 t1 = *(const float2*)(sp + (p0 + 1) * 34 + cp * 2);
            float2 t2 = *(const float2*)(sp + (p0 + 2) * 34 + cp * 2);
            float2 t3 = *(const float2*)(sp + (p0 + 3) * 34 + cp * 2);
            const int c0 = cp * 2, c1 = cp * 2 + 1;
            acc[0][0] = fmaf(t0.x, wc[c0][0], acc[0][0]); acc[0][1] = fmaf(t0.x, wc[c0][1], acc[0][1]);
            acc[1][0] = fmaf(t1.x, wc[c0][0], acc[1][0]); acc[1][1] = fmaf(t1.x, wc[c0][1], acc[1][1]);
            acc[2][0] = fmaf(t2.x, wc[c0][0], acc[2][0]); acc[2][1] = fmaf(t2.x, wc[c0][1], acc[2][1]);
            acc[3][0] = fmaf(t3.x, wc[c0][0], acc[3][0]); acc[3][1] = fmaf(t3.x, wc[c0][1], acc[3][1]);
            acc[0][0] = fmaf(t0.y, wc[c1][0], acc[0][0]); acc[0][1] = fmaf(t0.y, wc[c1][1], acc[0][1]);
            acc[1][0] = fmaf(t1.y, wc[c1][0], acc[1][0]); acc[1][1] = fmaf(t1.y, wc[c1][1], acc[1][1]);
            acc[2][0] = fmaf(t2.y, wc[c1][0], acc[2][0]); acc[2][1] = fmaf(t2.y, wc[c1][1], acc[2][1]);
            acc[3][0] = fmaf(t3.y, wc[c1][0], acc[3][0]); acc[3][1] = fmaf(t3.y, wc[c1][1], acc[3][1]);
        }
    };

    loadW(W0); sweep(sA);
    loadW(W1); sweep(sB);

    #pragma unroll
    for (int l = 0; l < 4; ++l) {
        int p = (int)base + p0 + l;
        int b, i, j, m; decodePos(p, b, i, j, m);
        float2 d2 = *(const float2*)(drp + (size_t)((b * nN + i) * nN + m) * 16 + d0);
        float2 cc2 = *(const float2*)(ccp + (size_t)((b * nN + j) * nN + m) * 16 + d0);
        float2 tb2 = *(const float2*)(tbp + (size_t)(b * nN + m) * 16 + d0);
        float mk = vm[b * nN + i] * vm[b * nN + j] * vm[b * nN + m];
        float2 o2;
        o2.x = (acc[l][0] + d2.x + cc2.x + tb2.x) * mk;
        o2.y = (acc[l][1] + d2.y + cc2.y + tb2.y) * mk;
        *(float2*)(out + (size_t)p * 16 + d0) = o2;
    }
}

} // anonymous namespace

// ---------------------------------------------------------------------------
extern "C" void kernel_launch(void* const* d_in, const int* in_sizes, int n_in,
                              void* d_out, int out_size, void* d_ws, size_t ws_size,
                              hipStream_t stream)
{
    (void)in_sizes; (void)n_in; (void)out_size; (void)ws_size;
    const float* x    = (const float*)d_in[0];
    const void*  mask = d_in[1];
    const float* bW0  = (const float*)d_in[2];
    const float* bb0  = (const float*)d_in[3];
    const float* lvW0 = (const float*)d_in[4];
    const float* lvb0 = (const float*)d_in[5];
    const float* lwW0 = (const float*)d_in[6];
    const float* lwb0 = (const float*)d_in[7];
    const float* loW0 = (const float*)d_in[8];
    const float* lob0 = (const float*)d_in[9];
    const float* bW1  = (const float*)d_in[10];
    const float* bb1  = (const float*)d_in[11];
    const float* lvW1 = (const float*)d_in[12];
    const float* lvb1 = (const float*)d_in[13];
    const float* lwW1 = (const float*)d_in[14];
    const float* lwb1 = (const float*)d_in[15];
    const float* loW1 = (const float*)d_in[16];
    const float* lob1 = (const float*)d_in[17];
    const float* fW   = (const float*)d_in[18];
    const float* fb   = (const float*)d_in[19];

    float* ws  = (float*)d_ws;
    float* t     = ws;                          // 14155776
    float* v     = ws + 14155776L;
    float* w     = ws + 28311552L;
    float* rows2 = ws + 42467328L;              // 2 * 294912
    float* cols2 = rows2 + 2 * 294912;          // 2 * 294912
    float* diag  = cols2 + 2 * 294912;          // 294912
    float* tot4  = diag + 294912;               // 4 * 6144
    float* drv   = tot4 + 4 * 6144;             // 294912
    float* ccv   = drv + 294912;                // 294912
    float* tbv   = ccv + 294912;                // 6144
    float* drw   = tbv + 6144;                  // 294912
    float* ccw   = drw + 294912;                // 294912
    float* tbw   = ccw + 294912;                // 6144
    float* cW    = tbw + 6144;                  // 4 * 6144 composed basic-W
    float* cb    = cW + 4 * 6144;               // 4 * 32 composed biases
    float* cWs   = cb + 128;                    // 2 * 1024 summed layer-0
    float* S     = cWs + 2048;                  // 128
    float* vm    = S + 128;                     // 192
    float* out   = (float*)d_out;

    k_prep<<<1, 256, 0, stream>>>(x, mask, vm, S);
    k_compose<<<4, 256, 0, stream>>>(bW0, bb0, lvW0, lwW0, bW1, bb1, lvW1, lwW1, cW, cb, cWs);

    // ---- layer 0 ----
    k_mix0<<<36, 256, 0, stream>>>(x, S, cW + 0,    cb + 0,  drv, ccv, tbv);
    k_mix0<<<36, 256, 0, stream>>>(x, S, cW + 6144, cb + 32, drw, ccw, tbw);
    k_vw<0><<<3456, 256, 0, stream>>>(x, vm, drv, ccv, tbv, drw, ccw, tbw,
                                      cWs,           // [ (W0+W1)@Wv | (W0+W1)@Ww ]
                                      cWs,           // unused in MODE0
                                      lvb0, lwb0, v, w);
    k_z<<<768, 256, 0, stream>>>(v, w, loW0, lob0, vm, t, rows2, cols2, diag, tot4);

    // ---- layer 1 ----
    k_mix<32><<<36, 256, 0, stream>>>(diag, rows2, cols2, tot4, cW + 12288, cb + 64, drv, ccv, tbv);
    k_mix<32><<<36, 256, 0, stream>>>(diag, rows2, cols2, tot4, cW + 18432, cb + 96, drw, ccw, tbw);
    k_vw<1><<<3456, 256, 0, stream>>>(t, vm, drv, ccv, tbv, drw, ccw, tbw,
                                      cW + 12288,    // [ W0@Wv | W1@Wv ]
                                      cW + 18432,    // [ W0@Ww | W1@Ww ]
                                      lvb1, lwb1, v, w);
    k_z<<<768, 256, 0, stream>>>(v, w, loW1, lob1, vm, t, rows2, cols2, diag, tot4);

    // ---- final snconv2 (uncomposed, 16ch) ----
    k_mix<16><<<36, 256, 0, stream>>>(diag, rows2, cols2, tot4, fW, fb, drv, ccv, tbv);
    k_final<<<3456, 256, 0, stream>>>(t, vm, drv, ccv, tbv, fW, fW + 512, out);
}

// Round 4
// 497.698 us; speedup vs baseline: 1.7293x; 1.1006x over previous
//
#include <hip/hip_runtime.h>
#include <cstdint>

// ---------------------------------------------------------------------------
// SnLocalDecoder: B=4, n=48, C=32. Round-13 = R12 + persistent-block pipelining
//  for k_vw and k_final (the convoy fix): 768 blocks x 9 chunks of 64
//  positions, double-buffered LDS, one barrier per chunk; next chunk's global
//  loads issue before the current chunk's compute so HBM latency hides under
//  FMAs regardless of block-level convoys. Weights in LDS once per block.
//  Launch merges: k_prep+k_compose -> k_prepcomp (5 blocks); k_mix0 pair and
//  k_mix<32> pair -> single 72-block launches. k_z unchanged from R12.
// ---------------------------------------------------------------------------

namespace {

constexpr int nB = 4, nN = 48, nC = 32;
constexpr int SJ_ = nN * nC;            // 1536
constexpr int SI_ = nN * SJ_;           // 73728
constexpr long SB_ = (long)nN * SI_;    // 3538944
constexpr int RP_ = 294912;             // rows-partial stride (2 partials)
constexpr int CP_ = 294912;             // cols-partial stride (2 partials)
constexpr int TP_ = 6144;               // tot-partial stride  (4 partials)

__device__ __forceinline__ void decodePos(int p, int& b, int& i, int& j, int& m) {
    m = p % nN; int r = p / nN;
    j = r % nN; r /= nN;
    i = r % nN; b = r / nN;
}

// ---------------------------------------------------------------------------
// blk 0..3: compose basic-conv weights with Wv/Ww; blk 4: mask/vm/S prep.
__global__ __launch_bounds__(256) void k_prepcomp(
    const float* __restrict__ x, const void* __restrict__ maskp,
    float* __restrict__ vm, float* __restrict__ S,
    const float* __restrict__ Wb0, const float* __restrict__ bb0,
    const float* __restrict__ Wv0, const float* __restrict__ Ww0,
    const float* __restrict__ Wb1, const float* __restrict__ bb1,
    const float* __restrict__ Wv1, const float* __restrict__ Ww1,
    float* __restrict__ cW, float* __restrict__ cb, float* __restrict__ cWs)
{
    __shared__ float Ws[1024];
    __shared__ float vmL[nB * nN];
    const int tid = threadIdx.x;

    if (blockIdx.x == 4) {                    // ---- prep ----
        const unsigned int w0 = *(const unsigned int*)maskp;
        const bool is_byte = (w0 == 0x01010101u);
        if (tid < nB * nN) {
            int b = tid / nN, i = tid % nN;
            long idx = ((long)(b * nN + i) * nN + i) * nN + i;
            int bit;
            if (is_byte) bit = (((const unsigned char*)maskp)[idx] != 0);
            else         bit = (((const int*)maskp)[idx] != 0);
            float f = bit ? 1.f : 0.f;
            vm[tid] = f; vmL[tid] = f;
        }
        __syncthreads();
        if (tid < nB * nC) {
            int b = tid >> 5, c = tid & 31;
            float s = 0.f;
            for (int j = 0; j < nN; ++j) s += x[(b * nN + j) * nC + c] * vmL[b * nN + j];
            S[tid] = s;
        }
        return;
    }

    const int blk = blockIdx.x;               // ---- compose ----
    const float* Wb = (blk < 2) ? Wb0 : Wb1;
    const float* bb = (blk < 2) ? bb0 : bb1;
    const float* Wr = (blk == 0) ? Wv0 : (blk == 1) ? Ww0 : (blk == 2) ? Wv1 : Ww1;
    for (int q = tid; q < 1024; q += 256) Ws[q] = Wr[q];
    __syncthreads();
    for (int q = tid; q < 6144; q += 256) {
        const int d = q & 31;
        const float* row = Wb + (q >> 5) * 32;
        float s = 0.f;
        #pragma unroll
        for (int e = 0; e < 32; ++e) s = fmaf(row[e], Ws[e * 32 + d], s);
        cW[blk * 6144 + q] = s;
    }
    if (blk < 2) {
        for (int q = tid; q < 1024; q += 256) {
            const int d = q & 31; const int c = q >> 5;
            const float* r0 = Wb + c * 32;
            const float* r1 = Wb + 1024 + c * 32;
            float s = 0.f;
            #pragma unroll
            for (int e = 0; e < 32; ++e) s = fmaf(r0[e] + r1[e], Ws[e * 32 + d], s);
            cWs[blk * 1024 + q] = s;
        }
    }
    if (tid < 32) {
        float s = 0.f;
        #pragma unroll
        for (int e = 0; e < 32; ++e) s = fmaf(bb[e], Ws[e * 32 + tid], s);
        cb[blk * 32 + tid] = s;
    }
}

// ---------------------------------------------------------------------------
// Layer-0 small snconv2 terms, closed form from x and S. Dual-set launch:
// blocks [0,36) use set a (v), [36,72) set b (w).
__global__ __launch_bounds__(256) void k_mix0(
    const float* __restrict__ x, const float* __restrict__ S,
    const float* __restrict__ Wb_a, const float* __restrict__ bias_a,
    float* __restrict__ dr_a, float* __restrict__ cc_a, float* __restrict__ tb_a,
    const float* __restrict__ Wb_b, const float* __restrict__ bias_b,
    float* __restrict__ dr_b, float* __restrict__ cc_b, float* __restrict__ tb_b)
{
    const int set = (blockIdx.x >= 36);
    const float* Wb   = set ? Wb_b   : Wb_a;
    const float* bias = set ? bias_b : bias_a;
    float* drp = set ? dr_b : dr_a;
    float* ccp = set ? cc_b : cc_a;
    float* tbp = set ? tb_b : tb_a;
    __shared__ float W2s[1024], W3s[1024], W4s[1024], W5s[1024], bs[32];
    const int tid = threadIdx.x;
    for (int q = tid; q < 1024; q += 256) {
        W2s[q] = Wb[2048 + q]; W3s[q] = Wb[3072 + q];
        W4s[q] = Wb[4096 + q]; W5s[q] = Wb[5120 + q];
    }
    if (tid < 32) bs[tid] = bias[tid];
    __syncthreads();
    const int id = (blockIdx.x - (set ? 36 : 0)) * 256 + tid;   // (b*48+i)*48+m
    const int m = id % nN; int r = id / nN; const int i = r % nN; const int b = r / nN;
    float odr[32], occ[32];
    #pragma unroll
    for (int d = 0; d < 32; ++d) { odr[d] = 0.f; occ[d] = 0.f; }
    for (int c2 = 0; c2 < 32; ++c2) {
        float xi = x[(b * nN + i) * nC + c2];
        float xm = x[(b * nN + m) * nC + c2];
        float sc = S[b * nC + c2];
        float A = xi * xi * xm;
        float R = xi * xm * sc * (1.f / nN);
        #pragma unroll
        for (int d = 0; d < 32; ++d) {
            odr[d] = fmaf(A, W2s[c2 * 32 + d], fmaf(R, W3s[c2 * 32 + d], odr[d]));
            occ[d] = fmaf(R, W4s[c2 * 32 + d], occ[d]);
        }
    }
    #pragma unroll
    for (int d = 0; d < 32; d += 4) {
        *(float4*)(drp + (size_t)id * 32 + d) = make_float4(odr[d], odr[d+1], odr[d+2], odr[d+3]);
        *(float4*)(ccp + (size_t)id * 32 + d) = make_float4(occ[d], occ[d+1], occ[d+2], occ[d+3]);
    }
    if (i == 0) {
        float ot[32];
        #pragma unroll
        for (int d = 0; d < 32; ++d) ot[d] = bs[d];
        for (int c2 = 0; c2 < 32; ++c2) {
            float xm = x[(b * nN + m) * nC + c2];
            float sc = S[b * nC + c2];
            float Tc = xm * sc * sc * (1.f / (nN * nN));
            #pragma unroll
            for (int d = 0; d < 32; ++d) ot[d] = fmaf(Tc, W5s[c2 * 32 + d], ot[d]);
        }
        for (int d = 0; d < 32; d += 4)
            *(float4*)(tbp + (size_t)(b * nN + m) * 32 + d) = make_float4(ot[d], ot[d+1], ot[d+2], ot[d+3]);
    }
}

// ---------------------------------------------------------------------------
// Small snconv2 terms from k_z's partials. Dual-set launch (same inputs).
template <int DOUT>
__global__ __launch_bounds__(256) void k_mix(
    const float* __restrict__ dgp, const float* __restrict__ rw2,
    const float* __restrict__ cl2, const float* __restrict__ tt4,
    const float* __restrict__ Wb_a, const float* __restrict__ bias_a,
    float* __restrict__ dr_a, float* __restrict__ cc_a, float* __restrict__ tb_a,
    const float* __restrict__ Wb_b, const float* __restrict__ bias_b,
    float* __restrict__ dr_b, float* __restrict__ cc_b, float* __restrict__ tb_b)
{
    const int set = (blockIdx.x >= 36);
    const float* Wb   = set ? Wb_b   : Wb_a;
    const float* bias = set ? bias_b : bias_a;
    float* drp = set ? dr_b : dr_a;
    float* ccp = set ? cc_b : cc_a;
    float* tbp = set ? tb_b : tb_a;
    __shared__ float W2s[32 * DOUT], W3s[32 * DOUT], W4s[32 * DOUT], W5s[32 * DOUT], bs[DOUT];
    const int tid = threadIdx.x;
    for (int q = tid; q < 32 * DOUT; q += 256) {
        W2s[q] = Wb[2 * 32 * DOUT + q]; W3s[q] = Wb[3 * 32 * DOUT + q];
        W4s[q] = Wb[4 * 32 * DOUT + q]; W5s[q] = Wb[5 * 32 * DOUT + q];
    }
    if (tid < DOUT) bs[tid] = bias[tid];
    __syncthreads();
    const int id = (blockIdx.x - (set ? 36 : 0)) * 256 + tid;
    const int m = id % nN; int r = id / nN; const int i = r % nN; const int b = r / nN;
    float odr[DOUT], occ[DOUT];
    #pragma unroll
    for (int d = 0; d < DOUT; ++d) { odr[d] = 0.f; occ[d] = 0.f; }
    for (int c2 = 0; c2 < 32; ++c2) {
        size_t q = (size_t)id * 32 + c2;
        float dg = dgp[q];
        float rw = (rw2[q] + rw2[q + RP_]) * (1.f / nN);
        float cl = (cl2[q] + cl2[q + CP_]) * (1.f / nN);
        #pragma unroll
        for (int d = 0; d < DOUT; ++d) {
            odr[d] = fmaf(dg, W2s[c2 * DOUT + d], fmaf(rw, W3s[c2 * DOUT + d], odr[d]));
            occ[d] = fmaf(cl, W4s[c2 * DOUT + d], occ[d]);
        }
    }
    #pragma unroll
    for (int d = 0; d < DOUT; d += 4) {
        *(float4*)(drp + (size_t)id * DOUT + d) = make_float4(odr[d], odr[d+1], odr[d+2], odr[d+3]);
        *(float4*)(ccp + (size_t)id * DOUT + d) = make_float4(occ[d], occ[d+1], occ[d+2], occ[d+3]);
    }
    if (i == 0) {
        float ot[DOUT];
        #pragma unroll
        for (int d = 0; d < DOUT; ++d) ot[d] = bs[d];
        for (int c2 = 0; c2 < 32; ++c2) {
            size_t q = (size_t)(b * nN + m) * 32 + c2;
            float tv = (tt4[q] + tt4[q + TP_] + tt4[q + 2 * TP_] + tt4[q + 3 * TP_])
                       * (1.f / (nN * nN));
            #pragma unroll
            for (int d = 0; d < DOUT; ++d) ot[d] = fmaf(tv, W5s[c2 * DOUT + d], ot[d]);
        }
        for (int d = 0; d < DOUT; d += 4)
            *(float4*)(tbp + (size_t)(b * nN + m) * DOUT + d) = make_float4(ot[d], ot[d+1], ot[d+2], ot[d+3]);
    }
}

// ---------------------------------------------------------------------------
// Persistent-block pipelined v/w producer (composed weights, dual acc).
// 768 blocks x 9 chunks of 64 positions, double-buffered LDS, 1 barrier/chunk.
#define FMA4(ar, tv, w4)                       \
    ar[0] = fmaf(tv, w4.x, ar[0]);             \
    ar[1] = fmaf(tv, w4.y, ar[1]);             \
    ar[2] = fmaf(tv, w4.z, ar[2]);             \
    ar[3] = fmaf(tv, w4.w, ar[3]);

template <int MODE>
__global__ __launch_bounds__(256) void k_vw(
    const float* __restrict__ src, const float* __restrict__ vm,
    const float* __restrict__ drv, const float* __restrict__ ccv, const float* __restrict__ tbv,
    const float* __restrict__ drw, const float* __restrict__ ccw, const float* __restrict__ tbw,
    const float* __restrict__ Wv2, const float* __restrict__ Ww2,
    const float* __restrict__ bv, const float* __restrict__ bw,
    float* __restrict__ vout, float* __restrict__ wout)
{
    constexpr int CH = 64;                     // positions per chunk
    constexpr int CS = CH * 34;                // 2176 floats per half
    constexpr int BUF = (MODE == 0) ? CS : 2 * CS;
    __shared__ float sT[2][BUF];
    __shared__ float wL[(MODE == 0) ? 2048 : 4096];
    const int tid = threadIdx.x;

    {   // weights -> LDS once per block
        float4* wl4 = (float4*)wL;
        for (int q = tid; q < 512; q += 256) wl4[q] = ((const float4*)Wv2)[q];
        if (MODE == 1)
            for (int q = tid; q < 512; q += 256) wl4[512 + q] = ((const float4*)Ww2)[q];
    }

    const int base0 = blockIdx.x * 9 * CH;
    float4 rA0, rA1, rB0, rB1;                 // staged chunk (named: no scratch)

    auto loadChunk = [&](int k) {
        const int cb = base0 + k * CH;
        {   const int q = tid; const int pl = q >> 3, cq = q & 7;
            const int p = cb + pl;
            if (MODE == 0) {
                int b, i, j, m; decodePos(p, b, i, j, m);
                float4 xi = *(const float4*)(src + (size_t)(b * nN + i) * nC + cq * 4);
                float4 xj = *(const float4*)(src + (size_t)(b * nN + j) * nC + cq * 4);
                float4 xm = *(const float4*)(src + (size_t)(b * nN + m) * nC + cq * 4);
                rA0.x = xi.x * xj.x * xm.x; rA0.y = xi.y * xj.y * xm.y;
                rA0.z = xi.z * xj.z * xm.z; rA0.w = xi.w * xj.w * xm.w;
            } else {
                rA0 = *(const float4*)(src + (size_t)p * nC + cq * 4);
                int b, i, j, m; decodePos(p, b, i, j, m);
                long pT = ((long)(b * nN + j) * nN + i) * nN + m;
                rB0 = *(const float4*)(src + pT * nC + cq * 4);
            }
        }
        {   const int q = 256 + tid; const int pl = q >> 3, cq = q & 7;
            const int p = cb + pl;
            if (MODE == 0) {
                int b, i, j, m; decodePos(p, b, i, j, m);
                float4 xi = *(const float4*)(src + (size_t)(b * nN + i) * nC + cq * 4);
                float4 xj = *(const float4*)(src + (size_t)(b * nN + j) * nC + cq * 4);
                float4 xm = *(const float4*)(src + (size_t)(b * nN + m) * nC + cq * 4);
                rA1.x = xi.x * xj.x * xm.x; rA1.y = xi.y * xj.y * xm.y;
                rA1.z = xi.z * xj.z * xm.z; rA1.w = xi.w * xj.w * xm.w;
            } else {
                rA1 = *(const float4*)(src + (size_t)p * nC + cq * 4);
                int b, i, j, m; decodePos(p, b, i, j, m);
                long pT = ((long)(b * nN + j) * nN + i) * nN + m;
                rB1 = *(const float4*)(src + pT * nC + cq * 4);
            }
        }
    };
    auto writeChunk = [&](int buf) {
        {   const int q = tid; const int o = (q >> 3) * 34 + (q & 7) * 4;
            sT[buf][o + 0] = rA0.x; sT[buf][o + 1] = rA0.y;
            sT[buf][o + 2] = rA0.z; sT[buf][o + 3] = rA0.w;
            if (MODE == 1) {
                sT[buf][CS + o + 0] = rB0.x; sT[buf][CS + o + 1] = rB0.y;
                sT[buf][CS + o + 2] = rB0.z; sT[buf][CS + o + 3] = rB0.w;
            }
        }
        {   const int q = 256 + tid; const int o = (q >> 3) * 34 + (q & 7) * 4;
            sT[buf][o + 0] = rA1.x; sT[buf][o + 1] = rA1.y;
            sT[buf][o + 2] = rA1.z; sT[buf][o + 3] = rA1.w;
            if (MODE == 1) {
                sT[buf][CS + o + 0] = rB1.x; sT[buf][CS + o + 1] = rB1.y;
                sT[buf][CS + o + 2] = rB1.z; sT[buf][CS + o + 3] = rB1.w;
            }
        }
    };

    loadChunk(0);
    writeChunk(0);
    __syncthreads();

    const int pt = tid >> 3, dq = tid & 7;
    const int p0 = pt * 2, d0 = dq * 4;

    for (int k = 0; k < 9; ++k) {
        const int cur = k & 1;
        if (k < 8) loadChunk(k + 1);
        __builtin_amdgcn_sched_barrier(0);     // loads issued before compute

        float accv[2][4], accw[2][4];
        #pragma unroll
        for (int l = 0; l < 2; ++l)
            #pragma unroll
            for (int d = 0; d < 4; ++d) { accv[l][d] = 0.f; accw[l][d] = 0.f; }

        const float* sp = sT[cur];
        #pragma unroll
        for (int cp = 0; cp < 16; ++cp) {      // sweep A
            float2 t0 = *(const float2*)(sp + (p0 + 0) * 34 + cp * 2);
            float2 t1 = *(const float2*)(sp + (p0 + 1) * 34 + cp * 2);
            const int c0 = cp * 2, c1 = cp * 2 + 1;
            const float* wwb = (MODE == 0) ? (wL + 1024) : (wL + 2048);
            float4 wv0 = *(const float4*)(wL + c0 * nC + d0);
            float4 wv1 = *(const float4*)(wL + c1 * nC + d0);
            float4 ww0 = *(const float4*)(wwb + c0 * nC + d0);
            float4 ww1 = *(const float4*)(wwb + c1 * nC + d0);
            FMA4(accv[0], t0.x, wv0); FMA4(accv[1], t1.x, wv0);
            FMA4(accv[0], t0.y, wv1); FMA4(accv[1], t1.y, wv1);
            FMA4(accw[0], t0.x, ww0); FMA4(accw[1], t1.x, ww0);
            FMA4(accw[0], t0.y, ww1); FMA4(accw[1], t1.y, ww1);
        }
        if (MODE == 1) {
            #pragma unroll
            for (int cp = 0; cp < 16; ++cp) {  // sweep B (tT)
                float2 t0 = *(const float2*)(sp + CS + (p0 + 0) * 34 + cp * 2);
                float2 t1 = *(const float2*)(sp + CS + (p0 + 1) * 34 + cp * 2);
                const int c0 = cp * 2, c1 = cp * 2 + 1;
                float4 wv0 = *(const float4*)(wL + 1024 + c0 * nC + d0);
                float4 wv1 = *(const float4*)(wL + 1024 + c1 * nC + d0);
                float4 ww0 = *(const float4*)(wL + 3072 + c0 * nC + d0);
                float4 ww1 = *(const float4*)(wL + 3072 + c1 * nC + d0);
                FMA4(accv[0], t0.x, wv0); FMA4(accv[1], t1.x, wv0);
                FMA4(accv[0], t0.y, wv1); FMA4(accv[1], t1.y, wv1);
                FMA4(accw[0], t0.x, ww0); FMA4(accw[1], t1.x, ww0);
                FMA4(accw[0], t0.y, ww1); FMA4(accw[1], t1.y, ww1);
            }
        }

        const int cb = base0 + k * CH;
        {   // epilogue v
            float4 b4 = *(const float4*)(bv + d0);
            #pragma unroll
            for (int l = 0; l < 2; ++l) {
                int p = cb + p0 + l;
                int b, i, j, m; decodePos(p, b, i, j, m);
                float4 d4 = *(const float4*)(drv + (size_t)((b * nN + i) * nN + m) * nC + d0);
                float4 c4 = *(const float4*)(ccv + (size_t)((b * nN + j) * nN + m) * nC + d0);
                float4 t4 = *(const float4*)(tbv + (size_t)(b * nN + m) * nC + d0);
                float mk = vm[b * nN + i] * vm[b * nN + j] * vm[b * nN + m];
                float4 o4;
                o4.x = (accv[l][0] + d4.x + c4.x + t4.x) * mk + b4.x;
                o4.y = (accv[l][1] + d4.y + c4.y + t4.y) * mk + b4.y;
                o4.z = (accv[l][2] + d4.z + c4.z + t4.z) * mk + b4.z;
                o4.w = (accv[l][3] + d4.w + c4.w + t4.w) * mk + b4.w;
                *(float4*)(vout + (size_t)p * nC + d0) = o4;
            }
        }
        {   // epilogue w
            float4 b4 = *(const float4*)(bw + d0);
            #pragma unroll
            for (int l = 0; l < 2; ++l) {
                int p = cb + p0 + l;
                int b, i, j, m; decodePos(p, b, i, j, m);
                float4 d4 = *(const float4*)(drw + (size_t)((b * nN + i) * nN + m) * nC + d0);
                float4 c4 = *(const float4*)(ccw + (size_t)((b * nN + j) * nN + m) * nC + d0);
                float4 t4 = *(const float4*)(tbw + (size_t)(b * nN + m) * nC + d0);
                float mk = vm[b * nN + i] * vm[b * nN + j] * vm[b * nN + m];
                float4 o4;
                o4.x = (accw[l][0] + d4.x + c4.x + t4.x) * mk + b4.x;
                o4.y = (accw[l][1] + d4.y + c4.y + t4.y) * mk + b4.y;
                o4.z = (accw[l][2] + d4.z + c4.z + t4.z) * mk + b4.z;
                o4.w = (accw[l][3] + d4.w + c4.w + t4.w) * mk + b4.w;
                *(float4*)(wout + (size_t)p * nC + d0) = o4;
            }
        }

        if (k < 8) {
            writeChunk((k + 1) & 1);           // other buffer: no race w/ readers
            __syncthreads();                   // next chunk visible to all
        }
    }
}

// ---------------------------------------------------------------------------
// z = V*W/n per (b,m); o-mix + relu + mask -> t; fused rows/cols/diag/tot
// partial reductions (no atomics). Tile 24i x 24j x 32c; 768 blocks.
__global__ __launch_bounds__(256, 3) void k_z(
    const float* __restrict__ v, const float* __restrict__ w,
    const float* __restrict__ Wo, const float* __restrict__ bo,
    const float* __restrict__ vm, float* __restrict__ tout,
    float* __restrict__ rows2, float* __restrict__ cols2,
    float* __restrict__ diag_, float* __restrict__ tot4)
{
    __shared__ float lds[12912];           // 51648 B -> 3 blocks/CU
    float* Vt = lds;                       // [kk][c][i]: kk*807 + c*25 + i
    float* Wt = lds + 6456;
    constexpr int ZS = 34;                 // z/out row stride (per position)
    constexpr int ZWO = 9792;              // Wo area
    constexpr int TOT0 = 10816;            // tot scratch [8][32]
    const int tid = threadIdx.x;
    const int blk = blockIdx.x;
    const int tl = blk & 3; const int bm = blk >> 2;
    const int it = tl >> 1, jt = tl & 1;
    const int b = bm / nN, m = bm % nN;
    const int c = tid & 31;
    const int g = tid >> 5;
    const int i3 = g >> 1, j2 = g & 1;     // i3 wave-uniform
    const int il0 = i3 * 6, jl0 = j2 * 12;
    const size_t posbase = (size_t)b * SB_ + (size_t)m * nC;

    float acc[6][12];
    #pragma unroll
    for (int l = 0; l < 6; ++l)
        #pragma unroll
        for (int u = 0; u < 12; ++u) acc[l][u] = 0.f;

    for (int kc = 0; kc < 6; ++kc) {
        if (kc) __syncthreads();
        #pragma unroll
        for (int rr = 0; rr < 6; ++rr) {          // V: 24i x 8k x 32c
            int q = rr * 256 + tid; int pos = q >> 3, cq = q & 7;
            int ii = pos >> 3, kk = pos & 7;
            float4 a = *(const float4*)(v + posbase + (size_t)(it * 24 + ii) * SI_
                                          + (size_t)(kc * 8 + kk) * SJ_ + cq * 4);
            float* dst = Vt + kk * 807 + (cq * 4) * 25 + ii;
            dst[0] = a.x; dst[25] = a.y; dst[50] = a.z; dst[75] = a.w;
        }
        #pragma unroll
        for (int rr = 0; rr < 6; ++rr) {          // W: 8k x 24j x 32c
            int q = rr * 256 + tid; int pos = q >> 3, cq = q & 7;
            int kk = pos / 24, jj = pos - kk * 24;
            float4 a = *(const float4*)(w + posbase + (size_t)(kc * 8 + kk) * SI_
                                          + (size_t)(jt * 24 + jj) * SJ_ + cq * 4);
            float* dst = Wt + kk * 807 + (cq * 4) * 25 + jj;
            dst[0] = a.x; dst[25] = a.y; dst[50] = a.z; dst[75] = a.w;
        }
        __syncthreads();
        #pragma unroll
        for (int kk = 0; kk < 8; ++kk) {
            float vf[6], wf[12];
            #pragma unroll
            for (int l = 0; l < 6; ++l) vf[l] = Vt[kk * 807 + c * 25 + il0 + l];
            #pragma unroll
            for (int u = 0; u < 12; ++u) wf[u] = Wt[kk * 807 + c * 25 + jl0 + u];
            #pragma unroll
            for (int l = 0; l < 6; ++l)
                #pragma unroll
                for (int u = 0; u < 12; ++u)
                    acc[l][u] = fmaf(vf[l], wf[u], acc[l][u]);
        }
    }
    __syncthreads();                               // staging area now reusable

    #pragma unroll
    for (int e = 0; e < 4; ++e)                    // Wo * (1/48)
        lds[ZWO + e * 256 + tid] = Wo[e * 256 + tid] * (1.f / nN);

    const int ptE = tid >> 3, dqE = tid & 7, d0 = dqE * 4;
    const float4 b4 = *(const float4*)(bo + d0);
    const float vmm = vm[b * nN + m];
    float colacc[3] = {0.f, 0.f, 0.f};
    float totacc = 0.f;

    for (int h = 0; h < 2; ++h) {
        if (h) __syncthreads();                    // protect h=0 reduction reads
        if ((i3 >> 1) == h) {                      // write this half's z
            int r0 = il0 - 12 * h;                 // 0 or 6
            #pragma unroll
            for (int l = 0; l < 6; ++l)
                #pragma unroll
                for (int u = 0; u < 12; ++u)
                    lds[((r0 + l) * 24 + jl0 + u) * ZS + c] = acc[l][u];
        }
        __syncthreads();                           // z + wo visible

        float oac[9][4];
        #pragma unroll
        for (int u = 0; u < 9; ++u)
            #pragma unroll
            for (int d = 0; d < 4; ++d) oac[u][d] = 0.f;
        #pragma unroll
        for (int c2 = 0; c2 < 32; ++c2) {
            float4 wo4 = *(const float4*)(lds + ZWO + c2 * 32 + d0);
            float zv[9];
            #pragma unroll
            for (int u = 0; u < 9; ++u) zv[u] = lds[(ptE * 9 + u) * ZS + c2];
            #pragma unroll
            for (int u = 0; u < 9; ++u) {
                oac[u][0] = fmaf(zv[u], wo4.x, oac[u][0]);
                oac[u][1] = fmaf(zv[u], wo4.y, oac[u][1]);
                oac[u][2] = fmaf(zv[u], wo4.z, oac[u][2]);
                oac[u][3] = fmaf(zv[u], wo4.w, oac[u][3]);
            }
        }
        __syncthreads();                           // all z reads done

        #pragma unroll
        for (int u = 0; u < 9; ++u) {
            int p = ptE * 9 + u;
            int rl = p / 24, jl = p - rl * 24;
            int gi = it * 24 + 12 * h + rl, gj = jt * 24 + jl;
            float mk = vm[b * nN + gi] * vm[b * nN + gj] * vmm;
            float4 o4;
            o4.x = fmaxf(oac[u][0] + b4.x, 0.f) * mk;
            o4.y = fmaxf(oac[u][1] + b4.y, 0.f) * mk;
            o4.z = fmaxf(oac[u][2] + b4.z, 0.f) * mk;
            o4.w = fmaxf(oac[u][3] + b4.w, 0.f) * mk;
            *(float4*)(tout + posbase + (size_t)gi * SI_ + (size_t)gj * SJ_ + d0) = o4;
            *(float2*)(lds + p * ZS + d0) = make_float2(o4.x, o4.y);
            *(float2*)(lds + p * ZS + d0 + 2) = make_float2(o4.z, o4.w);
        }
        __syncthreads();                           // out tile visible in LDS

        for (int rd = 0; rd < 2; ++rd) {
            int task = rd * 256 + tid;
            if (task < 384) {
                int i_r = task >> 5, c_r = task & 31;
                float rsum = 0.f;
                #pragma unroll
                for (int jl = 0; jl < 24; ++jl) rsum += lds[(i_r * 24 + jl) * ZS + c_r];
                int gi = it * 24 + 12 * h + i_r;
                rows2[(size_t)jt * RP_ + ((size_t)(b * nN + gi) * nN + m) * nC + c_r] = rsum;
                totacc += rsum;
                if (it == jt)
                    diag_[((size_t)(b * nN + gi) * nN + m) * nC + c_r] =
                        lds[(i_r * 24 + (12 * h + i_r)) * ZS + c_r];
            }
        }
        #pragma unroll
        for (int rr = 0; rr < 3; ++rr) {
            int task = rr * 256 + tid;
            int jl = task >> 5, c_c = task & 31;
            float csum = 0.f;
            #pragma unroll
            for (int il = 0; il < 12; ++il) csum += lds[(il * 24 + jl) * ZS + c_c];
            colacc[rr] += csum;
        }
    }

    #pragma unroll
    for (int rr = 0; rr < 3; ++rr) {
        int task = rr * 256 + tid;
        int jl = task >> 5, c_c = task & 31;
        cols2[(size_t)it * CP_ + ((size_t)(b * nN + jt * 24 + jl) * nN + m) * nC + c_c] = colacc[rr];
    }
    lds[TOT0 + g * 32 + c] = totacc;
    __syncthreads();
    if (tid < 32) {
        float s = 0.f;
        #pragma unroll
        for (int gg = 0; gg < 8; ++gg) s += lds[TOT0 + gg * 32 + tid];
        tot4[(size_t)(it * 2 + jt) * TP_ + (size_t)(b * nN + m) * nC + tid] = s;
    }
}

// ---------------------------------------------------------------------------
// Final snconv2 (C_out = 16), masked, direct to d_out. Persistent-block
// pipelined like k_vw: 768 blocks x 9 chunks of 64 positions, dbuf LDS.
__global__ __launch_bounds__(256) void k_final(
    const float* __restrict__ t, const float* __restrict__ vm,
    const float* __restrict__ drp, const float* __restrict__ ccp, const float* __restrict__ tbp,
    const float* __restrict__ W0, const float* __restrict__ W1,
    float* __restrict__ out)
{
    constexpr int CH = 64, CS = CH * 34;
    __shared__ float sT[2][2 * CS];
    __shared__ float wL[1024];                 // [W0 | W1], 32x16 each
    const int tid = threadIdx.x;

    {
        float4* wl4 = (float4*)wL;
        for (int q = tid; q < 128; q += 256) wl4[q] = ((const float4*)W0)[q];
        for (int q = tid; q < 128; q += 256) wl4[128 + q] = ((const float4*)W1)[q];
    }

    const int base0 = blockIdx.x * 9 * CH;
    float4 rA0, rA1, rB0, rB1;

    auto loadChunk = [&](int k) {
        const int cb = base0 + k * CH;
        {   const int q = tid; const int pl = q >> 3, cq = q & 7;
            const int p = cb + pl;
            rA0 = *(const float4*)(t + (size_t)p * nC + cq * 4);
            int b, i, j, m; decodePos(p, b, i, j, m);
            long pT = ((long)(b * nN + j) * nN + i) * nN + m;
            rB0 = *(const float4*)(t + pT * nC + cq * 4);
        }
        {   const int q = 256 + tid; const int pl = q >> 3, cq = q & 7;
            const int p = cb + pl;
            rA1 = *(const float4*)(t + (size_t)p * nC + cq * 4);
            int b, i, j, m; decodePos(p, b, i, j, m);
            long pT = ((long)(b * nN + j) * nN + i) * nN + m;
            rB1 = *(const float4*)(t + pT * nC + cq * 4);
        }
    };
    auto writeChunk = [&](int buf) {
        {   const int q = tid; const int o = (q >> 3) * 34 + (q & 7) * 4;
            sT[buf][o + 0] = rA0.x; sT[buf][o + 1] = rA0.y;
            sT[buf][o + 2] = rA0.z; sT[buf][o + 3] = rA0.w;
            sT[buf][CS + o + 0] = rB0.x; sT[buf][CS + o + 1] = rB0.y;
            sT[buf][CS + o + 2] = rB0.z; sT[buf][CS + o + 3] = rB0.w;
        }
        {   const int q = 256 + tid; const int o = (q >> 3) * 34 + (q & 7) * 4;
            sT[buf][o + 0] = rA1.x; sT[buf][o + 1] = rA1.y;
            sT[buf][o + 2] = rA1.z; sT[buf][o + 3] = rA1.w;
            sT[buf][CS + o + 0] = rB1.x; sT[buf][CS + o + 1] = rB1.y;
            sT[buf][CS + o + 2] = rB1.z; sT[buf][CS + o + 3] = rB1.w;
        }
    };

    loadChunk(0);
    writeChunk(0);
    __syncthreads();

    const int pt = tid >> 3, dq = tid & 7;
    const int p0 = pt * 2, d0 = dq * 2;

    for (int k = 0; k < 9; ++k) {
        const int cur = k & 1;
        if (k < 8) loadChunk(k + 1);
        __builtin_amdgcn_sched_barrier(0);

        float acc[2][2];
        acc[0][0] = 0.f; acc[0][1] = 0.f; acc[1][0] = 0.f; acc[1][1] = 0.f;
        const float* sp = sT[cur];
        #pragma unroll
        for (int cp = 0; cp < 16; ++cp) {      // sweep A with W0
            float2 t0 = *(const float2*)(sp + (p0 + 0) * 34 + cp * 2);
            float2 t1 = *(const float2*)(sp + (p0 + 1) * 34 + cp * 2);
            const int c0 = cp * 2, c1 = cp * 2 + 1;
            float2 w0 = *(const float2*)(wL + c0 * 16 + d0);
            float2 w1 = *(const float2*)(wL + c1 * 16 + d0);
            acc[0][0] = fmaf(t0.x, w0.x, acc[0][0]); acc[0][1] = fmaf(t0.x, w0.y, acc[0][1]);
            acc[1][0] = fmaf(t1.x, w0.x, acc[1][0]); acc[1][1] = fmaf(t1.x, w0.y, acc[1][1]);
            acc[0][0] = fmaf(t0.y, w1.x, acc[0][0]); acc[0][1] = fmaf(t0.y, w1.y, acc[0][1]);
            acc[1][0] = fmaf(t1.y, w1.x, acc[1][0]); acc[1][1] = fmaf(t1.y, w1.y, acc[1][1]);
        }
        #pragma unroll
        for (int cp = 0; cp < 16; ++cp) {      // sweep B with W1
            float2 t0 = *(const float2*)(sp + CS + (p0 + 0) * 34 + cp * 2);
            float2 t1 = *(const float2*)(sp + CS + (p0 + 1) * 34 + cp * 2);
            const int c0 = cp * 2, c1 = cp * 2 + 1;
            float2 w0 = *(const float2*)(wL + 512 + c0 * 16 + d0);
            float2 w1 = *(const float2*)(wL + 512 + c1 * 16 + d0);
            acc[0][0] = fmaf(t0.x, w0.x, acc[0][0]); acc[0][1] = fmaf(t0.x, w0.y, acc[0][1]);
            acc[1][0] = fmaf(t1.x, w0.x, acc[1][0]); acc[1][1] = fmaf(t1.x, w0.y, acc[1][1]);
            acc[0][0] = fmaf(t0.y, w1.x, acc[0][0]); acc[0][1] = fmaf(t0.y, w1.y, acc[0][1]);
            acc[1][0] = fmaf(t1.y, w1.x, acc[1][0]); acc[1][1] = fmaf(t1.y, w1.y, acc[1][1]);
        }

        const int cb = base0 + k * CH;
        #pragma unroll
        for (int l = 0; l < 2; ++l) {
            int p = cb + p0 + l;
            int b, i, j, m; decodePos(p, b, i, j, m);
            float2 d2 = *(const float2*)(drp + (size_t)((b * nN + i) * nN + m) * 16 + d0);
            float2 cc2 = *(const float2*)(ccp + (size_t)((b * nN + j) * nN + m) * 16 + d0);
            float2 tb2 = *(const float2*)(tbp + (size_t)(b * nN + m) * 16 + d0);
            float mk = vm[b * nN + i] * vm[b * nN + j] * vm[b * nN + m];
            float2 o2;
            o2.x = (acc[l][0] + d2.x + cc2.x + tb2.x) * mk;
            o2.y = (acc[l][1] + d2.y + cc2.y + tb2.y) * mk;
            *(float2*)(out + (size_t)p * 16 + d0) = o2;
        }

        if (k < 8) {
            writeChunk((k + 1) & 1);
            __syncthreads();
        }
    }
}

} // anonymous namespace

// ---------------------------------------------------------------------------
extern "C" void kernel_launch(void* const* d_in, const int* in_sizes, int n_in,
                              void* d_out, int out_size, void* d_ws, size_t ws_size,
                              hipStream_t stream)
{
    (void)in_sizes; (void)n_in; (void)out_size; (void)ws_size;
    const float* x    = (const float*)d_in[0];
    const void*  mask = d_in[1];
    const float* bW0  = (const float*)d_in[2];
    const float* bb0  = (const float*)d_in[3];
    const float* lvW0 = (const float*)d_in[4];
    const float* lvb0 = (const float*)d_in[5];
    const float* lwW0 = (const float*)d_in[6];
    const float* lwb0 = (const float*)d_in[7];
    const float* loW0 = (const float*)d_in[8];
    const float* lob0 = (const float*)d_in[9];
    const float* bW1  = (const float*)d_in[10];
    const float* bb1  = (const float*)d_in[11];
    const float* lvW1 = (const float*)d_in[12];
    const float* lvb1 = (const float*)d_in[13];
    const float* lwW1 = (const float*)d_in[14];
    const float* lwb1 = (const float*)d_in[15];
    const float* loW1 = (const float*)d_in[16];
    const float* lob1 = (const float*)d_in[17];
    const float* fW   = (const float*)d_in[18];
    const float* fb   = (const float*)d_in[19];

    float* ws  = (float*)d_ws;
    float* t     = ws;                          // 14155776
    float* v     = ws + 14155776L;
    float* w     = ws + 28311552L;
    float* rows2 = ws + 42467328L;              // 2 * 294912
    float* cols2 = rows2 + 2 * 294912;          // 2 * 294912
    float* diag  = cols2 + 2 * 294912;          // 294912
    float* tot4  = diag + 294912;               // 4 * 6144
    float* drv   = tot4 + 4 * 6144;             // 294912
    float* ccv   = drv + 294912;                // 294912
    float* tbv   = ccv + 294912;                // 6144
    float* drw   = tbv + 6144;                  // 294912
    float* ccw   = drw + 294912;                // 294912
    float* tbw   = ccw + 294912;                // 6144
    float* cW    = tbw + 6144;                  // 4 * 6144 composed basic-W
    float* cb    = cW + 4 * 6144;               // 4 * 32 composed biases
    float* cWs   = cb + 128;                    // 2 * 1024 summed layer-0
    float* S     = cWs + 2048;                  // 128
    float* vm    = S + 128;                     // 192
    float* out   = (float*)d_out;

    k_prepcomp<<<5, 256, 0, stream>>>(x, mask, vm, S,
                                      bW0, bb0, lvW0, lwW0,
                                      bW1, bb1, lvW1, lwW1, cW, cb, cWs);

    // ---- layer 0 ----
    k_mix0<<<72, 256, 0, stream>>>(x, S,
                                   cW + 0,    cb + 0,  drv, ccv, tbv,
                                   cW + 6144, cb + 32, drw, ccw, tbw);
    k_vw<0><<<768, 256, 0, stream>>>(x, vm, drv, ccv, tbv, drw, ccw, tbw,
                                     cWs,        // [ (W0+W1)@Wv | (W0+W1)@Ww ]
                                     cWs,        // unused in MODE0
                                     lvb0, lwb0, v, w);
    k_z<<<768, 256, 0, stream>>>(v, w, loW0, lob0, vm, t, rows2, cols2, diag, tot4);

    // ---- layer 1 ----
    k_mix<32><<<72, 256, 0, stream>>>(diag, rows2, cols2, tot4,
                                      cW + 12288, cb + 64, drv, ccv, tbv,
                                      cW + 18432, cb + 96, drw, ccw, tbw);
    k_vw<1><<<768, 256, 0, stream>>>(t, vm, drv, ccv, tbv, drw, ccw, tbw,
                                     cW + 12288,  // [ W0@Wv | W1@Wv ]
                                     cW + 18432,  // [ W0@Ww | W1@Ww ]
                                     lvb1, lwb1, v, w);
    k_z<<<768, 256, 0, stream>>>(v, w, loW1, lob1, vm, t, rows2, cols2, diag, tot4);

    // ---- final snconv2 (uncomposed, 16ch) ----
    k_mix<16><<<36, 256, 0, stream>>>(diag, rows2, cols2, tot4,
                                      fW, fb, drv, ccv, tbv,
                                      fW, fb, drv, ccv, tbv);
    k_final<<<768, 256, 0, stream>>>(t, vm, drv, ccv, tbv, fW, fW + 512, out);
}

// Round 5
// 462.437 us; speedup vs baseline: 1.8611x; 1.0763x over previous
//
#include <hip/hip_runtime.h>
#include <cstdint>

// ---------------------------------------------------------------------------
// SnLocalDecoder: B=4, n=48, C=32. Round-14 = R13 + k_z convoy fix:
//  k_z now double-buffers its K-staging (kc chunks of 4, 2x6456-float LDS
//  buffers in the same 51.6KB footprint; epilogue z-area still overlays).
//  Per chunk: issue 6 register-staged float4 loads -> compute current buf ->
//  write regs to other buf -> ONE barrier. Plus XCD-sibling blockIdx swizzle:
//  the 4 tiles of one (b,m) share V/W panels; mapping them to the same XCD
//  turns the 2x panel re-read into L2 hits. k_vw/k_final/mixes from R13.
// ---------------------------------------------------------------------------

namespace {

constexpr int nB = 4, nN = 48, nC = 32;
constexpr int SJ_ = nN * nC;            // 1536
constexpr int SI_ = nN * SJ_;           // 73728
constexpr long SB_ = (long)nN * SI_;    // 3538944
constexpr int RP_ = 294912;             // rows-partial stride (2 partials)
constexpr int CP_ = 294912;             // cols-partial stride (2 partials)
constexpr int TP_ = 6144;               // tot-partial stride  (4 partials)

__device__ __forceinline__ void decodePos(int p, int& b, int& i, int& j, int& m) {
    m = p % nN; int r = p / nN;
    j = r % nN; r /= nN;
    i = r % nN; b = r / nN;
}

// ---------------------------------------------------------------------------
// blk 0..3: compose basic-conv weights with Wv/Ww; blk 4: mask/vm/S prep.
__global__ __launch_bounds__(256) void k_prepcomp(
    const float* __restrict__ x, const void* __restrict__ maskp,
    float* __restrict__ vm, float* __restrict__ S,
    const float* __restrict__ Wb0, const float* __restrict__ bb0,
    const float* __restrict__ Wv0, const float* __restrict__ Ww0,
    const float* __restrict__ Wb1, const float* __restrict__ bb1,
    const float* __restrict__ Wv1, const float* __restrict__ Ww1,
    float* __restrict__ cW, float* __restrict__ cb, float* __restrict__ cWs)
{
    __shared__ float Ws[1024];
    __shared__ float vmL[nB * nN];
    const int tid = threadIdx.x;

    if (blockIdx.x == 4) {                    // ---- prep ----
        const unsigned int w0 = *(const unsigned int*)maskp;
        const bool is_byte = (w0 == 0x01010101u);
        if (tid < nB * nN) {
            int b = tid / nN, i = tid % nN;
            long idx = ((long)(b * nN + i) * nN + i) * nN + i;
            int bit;
            if (is_byte) bit = (((const unsigned char*)maskp)[idx] != 0);
            else         bit = (((const int*)maskp)[idx] != 0);
            float f = bit ? 1.f : 0.f;
            vm[tid] = f; vmL[tid] = f;
        }
        __syncthreads();
        if (tid < nB * nC) {
            int b = tid >> 5, c = tid & 31;
            float s = 0.f;
            for (int j = 0; j < nN; ++j) s += x[(b * nN + j) * nC + c] * vmL[b * nN + j];
            S[tid] = s;
        }
        return;
    }

    const int blk = blockIdx.x;               // ---- compose ----
    const float* Wb = (blk < 2) ? Wb0 : Wb1;
    const float* bb = (blk < 2) ? bb0 : bb1;
    const float* Wr = (blk == 0) ? Wv0 : (blk == 1) ? Ww0 : (blk == 2) ? Wv1 : Ww1;
    for (int q = tid; q < 1024; q += 256) Ws[q] = Wr[q];
    __syncthreads();
    for (int q = tid; q < 6144; q += 256) {
        const int d = q & 31;
        const float* row = Wb + (q >> 5) * 32;
        float s = 0.f;
        #pragma unroll
        for (int e = 0; e < 32; ++e) s = fmaf(row[e], Ws[e * 32 + d], s);
        cW[blk * 6144 + q] = s;
    }
    if (blk < 2) {
        for (int q = tid; q < 1024; q += 256) {
            const int d = q & 31; const int c = q >> 5;
            const float* r0 = Wb + c * 32;
            const float* r1 = Wb + 1024 + c * 32;
            float s = 0.f;
            #pragma unroll
            for (int e = 0; e < 32; ++e) s = fmaf(r0[e] + r1[e], Ws[e * 32 + d], s);
            cWs[blk * 1024 + q] = s;
        }
    }
    if (tid < 32) {
        float s = 0.f;
        #pragma unroll
        for (int e = 0; e < 32; ++e) s = fmaf(bb[e], Ws[e * 32 + tid], s);
        cb[blk * 32 + tid] = s;
    }
}

// ---------------------------------------------------------------------------
// Layer-0 small snconv2 terms, closed form from x and S. Dual-set launch:
// blocks [0,36) use set a (v), [36,72) set b (w).
__global__ __launch_bounds__(256) void k_mix0(
    const float* __restrict__ x, const float* __restrict__ S,
    const float* __restrict__ Wb_a, const float* __restrict__ bias_a,
    float* __restrict__ dr_a, float* __restrict__ cc_a, float* __restrict__ tb_a,
    const float* __restrict__ Wb_b, const float* __restrict__ bias_b,
    float* __restrict__ dr_b, float* __restrict__ cc_b, float* __restrict__ tb_b)
{
    const int set = (blockIdx.x >= 36);
    const float* Wb   = set ? Wb_b   : Wb_a;
    const float* bias = set ? bias_b : bias_a;
    float* drp = set ? dr_b : dr_a;
    float* ccp = set ? cc_b : cc_a;
    float* tbp = set ? tb_b : tb_a;
    __shared__ float W2s[1024], W3s[1024], W4s[1024], W5s[1024], bs[32];
    const int tid = threadIdx.x;
    for (int q = tid; q < 1024; q += 256) {
        W2s[q] = Wb[2048 + q]; W3s[q] = Wb[3072 + q];
        W4s[q] = Wb[4096 + q]; W5s[q] = Wb[5120 + q];
    }
    if (tid < 32) bs[tid] = bias[tid];
    __syncthreads();
    const int id = (blockIdx.x - (set ? 36 : 0)) * 256 + tid;   // (b*48+i)*48+m
    const int m = id % nN; int r = id / nN; const int i = r % nN; const int b = r / nN;
    float odr[32], occ[32];
    #pragma unroll
    for (int d = 0; d < 32; ++d) { odr[d] = 0.f; occ[d] = 0.f; }
    for (int c2 = 0; c2 < 32; ++c2) {
        float xi = x[(b * nN + i) * nC + c2];
        float xm = x[(b * nN + m) * nC + c2];
        float sc = S[b * nC + c2];
        float A = xi * xi * xm;
        float R = xi * xm * sc * (1.f / nN);
        #pragma unroll
        for (int d = 0; d < 32; ++d) {
            odr[d] = fmaf(A, W2s[c2 * 32 + d], fmaf(R, W3s[c2 * 32 + d], odr[d]));
            occ[d] = fmaf(R, W4s[c2 * 32 + d], occ[d]);
        }
    }
    #pragma unroll
    for (int d = 0; d < 32; d += 4) {
        *(float4*)(drp + (size_t)id * 32 + d) = make_float4(odr[d], odr[d+1], odr[d+2], odr[d+3]);
        *(float4*)(ccp + (size_t)id * 32 + d) = make_float4(occ[d], occ[d+1], occ[d+2], occ[d+3]);
    }
    if (i == 0) {
        float ot[32];
        #pragma unroll
        for (int d = 0; d < 32; ++d) ot[d] = bs[d];
        for (int c2 = 0; c2 < 32; ++c2) {
            float xm = x[(b * nN + m) * nC + c2];
            float sc = S[b * nC + c2];
            float Tc = xm * sc * sc * (1.f / (nN * nN));
            #pragma unroll
            for (int d = 0; d < 32; ++d) ot[d] = fmaf(Tc, W5s[c2 * 32 + d], ot[d]);
        }
        for (int d = 0; d < 32; d += 4)
            *(float4*)(tbp + (size_t)(b * nN + m) * 32 + d) = make_float4(ot[d], ot[d+1], ot[d+2], ot[d+3]);
    }
}

// ---------------------------------------------------------------------------
// Small snconv2 terms from k_z's partials. Dual-set launch (same inputs).
template <int DOUT>
__global__ __launch_bounds__(256) void k_mix(
    const float* __restrict__ dgp, const float* __restrict__ rw2,
    const float* __restrict__ cl2, const float* __restrict__ tt4,
    const float* __restrict__ Wb_a, const float* __restrict__ bias_a,
    float* __restrict__ dr_a, float* __restrict__ cc_a, float* __restrict__ tb_a,
    const float* __restrict__ Wb_b, const float* __restrict__ bias_b,
    float* __restrict__ dr_b, float* __restrict__ cc_b, float* __restrict__ tb_b)
{
    const int set = (blockIdx.x >= 36);
    const float* Wb   = set ? Wb_b   : Wb_a;
    const float* bias = set ? bias_b : bias_a;
    float* drp = set ? dr_b : dr_a;
    float* ccp = set ? cc_b : cc_a;
    float* tbp = set ? tb_b : tb_a;
    __shared__ float W2s[32 * DOUT], W3s[32 * DOUT], W4s[32 * DOUT], W5s[32 * DOUT], bs[DOUT];
    const int tid = threadIdx.x;
    for (int q = tid; q < 32 * DOUT; q += 256) {
        W2s[q] = Wb[2 * 32 * DOUT + q]; W3s[q] = Wb[3 * 32 * DOUT + q];
        W4s[q] = Wb[4 * 32 * DOUT + q]; W5s[q] = Wb[5 * 32 * DOUT + q];
    }
    if (tid < DOUT) bs[tid] = bias[tid];
    __syncthreads();
    const int id = (blockIdx.x - (set ? 36 : 0)) * 256 + tid;
    const int m = id % nN; int r = id / nN; const int i = r % nN; const int b = r / nN;
    float odr[DOUT], occ[DOUT];
    #pragma unroll
    for (int d = 0; d < DOUT; ++d) { odr[d] = 0.f; occ[d] = 0.f; }
    for (int c2 = 0; c2 < 32; ++c2) {
        size_t q = (size_t)id * 32 + c2;
        float dg = dgp[q];
        float rw = (rw2[q] + rw2[q + RP_]) * (1.f / nN);
        float cl = (cl2[q] + cl2[q + CP_]) * (1.f / nN);
        #pragma unroll
        for (int d = 0; d < DOUT; ++d) {
            odr[d] = fmaf(dg, W2s[c2 * DOUT + d], fmaf(rw, W3s[c2 * DOUT + d], odr[d]));
            occ[d] = fmaf(cl, W4s[c2 * DOUT + d], occ[d]);
        }
    }
    #pragma unroll
    for (int d = 0; d < DOUT; d += 4) {
        *(float4*)(drp + (size_t)id * DOUT + d) = make_float4(odr[d], odr[d+1], odr[d+2], odr[d+3]);
        *(float4*)(ccp + (size_t)id * DOUT + d) = make_float4(occ[d], occ[d+1], occ[d+2], occ[d+3]);
    }
    if (i == 0) {
        float ot[DOUT];
        #pragma unroll
        for (int d = 0; d < DOUT; ++d) ot[d] = bs[d];
        for (int c2 = 0; c2 < 32; ++c2) {
            size_t q = (size_t)(b * nN + m) * 32 + c2;
            float tv = (tt4[q] + tt4[q + TP_] + tt4[q + 2 * TP_] + tt4[q + 3 * TP_])
                       * (1.f / (nN * nN));
            #pragma unroll
            for (int d = 0; d < DOUT; ++d) ot[d] = fmaf(tv, W5s[c2 * DOUT + d], ot[d]);
        }
        for (int d = 0; d < DOUT; d += 4)
            *(float4*)(tbp + (size_t)(b * nN + m) * DOUT + d) = make_float4(ot[d], ot[d+1], ot[d+2], ot[d+3]);
    }
}

// ---------------------------------------------------------------------------
// Persistent-block pipelined v/w producer (composed weights, dual acc).
// 768 blocks x 9 chunks of 64 positions, double-buffered LDS, 1 barrier/chunk.
#define FMA4(ar, tv, w4)                       \
    ar[0] = fmaf(tv, w4.x, ar[0]);             \
    ar[1] = fmaf(tv, w4.y, ar[1]);             \
    ar[2] = fmaf(tv, w4.z, ar[2]);             \
    ar[3] = fmaf(tv, w4.w, ar[3]);

template <int MODE>
__global__ __launch_bounds__(256) void k_vw(
    const float* __restrict__ src, const float* __restrict__ vm,
    const float* __restrict__ drv, const float* __restrict__ ccv, const float* __restrict__ tbv,
    const float* __restrict__ drw, const float* __restrict__ ccw, const float* __restrict__ tbw,
    const float* __restrict__ Wv2, const float* __restrict__ Ww2,
    const float* __restrict__ bv, const float* __restrict__ bw,
    float* __restrict__ vout, float* __restrict__ wout)
{
    constexpr int CH = 64;                     // positions per chunk
    constexpr int CS = CH * 34;                // 2176 floats per half
    constexpr int BUF = (MODE == 0) ? CS : 2 * CS;
    __shared__ float sT[2][BUF];
    __shared__ float wL[(MODE == 0) ? 2048 : 4096];
    const int tid = threadIdx.x;

    {   // weights -> LDS once per block
        float4* wl4 = (float4*)wL;
        for (int q = tid; q < 512; q += 256) wl4[q] = ((const float4*)Wv2)[q];
        if (MODE == 1)
            for (int q = tid; q < 512; q += 256) wl4[512 + q] = ((const float4*)Ww2)[q];
    }

    const int base0 = blockIdx.x * 9 * CH;
    float4 rA0, rA1, rB0, rB1;                 // staged chunk (named: no scratch)

    auto loadChunk = [&](int k) {
        const int cb = base0 + k * CH;
        {   const int q = tid; const int pl = q >> 3, cq = q & 7;
            const int p = cb + pl;
            if (MODE == 0) {
                int b, i, j, m; decodePos(p, b, i, j, m);
                float4 xi = *(const float4*)(src + (size_t)(b * nN + i) * nC + cq * 4);
                float4 xj = *(const float4*)(src + (size_t)(b * nN + j) * nC + cq * 4);
                float4 xm = *(const float4*)(src + (size_t)(b * nN + m) * nC + cq * 4);
                rA0.x = xi.x * xj.x * xm.x; rA0.y = xi.y * xj.y * xm.y;
                rA0.z = xi.z * xj.z * xm.z; rA0.w = xi.w * xj.w * xm.w;
            } else {
                rA0 = *(const float4*)(src + (size_t)p * nC + cq * 4);
                int b, i, j, m; decodePos(p, b, i, j, m);
                long pT = ((long)(b * nN + j) * nN + i) * nN + m;
                rB0 = *(const float4*)(src + pT * nC + cq * 4);
            }
        }
        {   const int q = 256 + tid; const int pl = q >> 3, cq = q & 7;
            const int p = cb + pl;
            if (MODE == 0) {
                int b, i, j, m; decodePos(p, b, i, j, m);
                float4 xi = *(const float4*)(src + (size_t)(b * nN + i) * nC + cq * 4);
                float4 xj = *(const float4*)(src + (size_t)(b * nN + j) * nC + cq * 4);
                float4 xm = *(const float4*)(src + (size_t)(b * nN + m) * nC + cq * 4);
                rA1.x = xi.x * xj.x * xm.x; rA1.y = xi.y * xj.y * xm.y;
                rA1.z = xi.z * xj.z * xm.z; rA1.w = xi.w * xj.w * xm.w;
            } else {
                rA1 = *(const float4*)(src + (size_t)p * nC + cq * 4);
                int b, i, j, m; decodePos(p, b, i, j, m);
                long pT = ((long)(b * nN + j) * nN + i) * nN + m;
                rB1 = *(const float4*)(src + pT * nC + cq * 4);
            }
        }
    };
    auto writeChunk = [&](int buf) {
        {   const int q = tid; const int o = (q >> 3) * 34 + (q & 7) * 4;
            sT[buf][o + 0] = rA0.x; sT[buf][o + 1] = rA0.y;
            sT[buf][o + 2] = rA0.z; sT[buf][o + 3] = rA0.w;
            if (MODE == 1) {
                sT[buf][CS + o + 0] = rB0.x; sT[buf][CS + o + 1] = rB0.y;
                sT[buf][CS + o + 2] = rB0.z; sT[buf][CS + o + 3] = rB0.w;
            }
        }
        {   const int q = 256 + tid; const int o = (q >> 3) * 34 + (q & 7) * 4;
            sT[buf][o + 0] = rA1.x; sT[buf][o + 1] = rA1.y;
            sT[buf][o + 2] = rA1.z; sT[buf][o + 3] = rA1.w;
            if (MODE == 1) {
                sT[buf][CS + o + 0] = rB1.x; sT[buf][CS + o + 1] = rB1.y;
                sT[buf][CS + o + 2] = rB1.z; sT[buf][CS + o + 3] = rB1.w;
            }
        }
    };

    loadChunk(0);
    writeChunk(0);
    __syncthreads();

    const int pt = tid >> 3, dq = tid & 7;
    const int p0 = pt * 2, d0 = dq * 4;

    for (int k = 0; k < 9; ++k) {
        const int cur = k & 1;
        if (k < 8) loadChunk(k + 1);
        __builtin_amdgcn_sched_barrier(0);     // loads issued before compute

        float accv[2][4], accw[2][4];
        #pragma unroll
        for (int l = 0; l < 2; ++l)
            #pragma unroll
            for (int d = 0; d < 4; ++d) { accv[l][d] = 0.f; accw[l][d] = 0.f; }

        const float* sp = sT[cur];
        #pragma unroll
        for (int cp = 0; cp < 16; ++cp) {      // sweep A
            float2 t0 = *(const float2*)(sp + (p0 + 0) * 34 + cp * 2);
            float2 t1 = *(const float2*)(sp + (p0 + 1) * 34 + cp * 2);
            const int c0 = cp * 2, c1 = cp * 2 + 1;
            const float* wwb = (MODE == 0) ? (wL + 1024) : (wL + 2048);
            float4 wv0 = *(const float4*)(wL + c0 * nC + d0);
            float4 wv1 = *(const float4*)(wL + c1 * nC + d0);
            float4 ww0 = *(const float4*)(wwb + c0 * nC + d0);
            float4 ww1 = *(const float4*)(wwb + c1 * nC + d0);
            FMA4(accv[0], t0.x, wv0); FMA4(accv[1], t1.x, wv0);
            FMA4(accv[0], t0.y, wv1); FMA4(accv[1], t1.y, wv1);
            FMA4(accw[0], t0.x, ww0); FMA4(accw[1], t1.x, ww0);
            FMA4(accw[0], t0.y, ww1); FMA4(accw[1], t1.y, ww1);
        }
        if (MODE == 1) {
            #pragma unroll
            for (int cp = 0; cp < 16; ++cp) {  // sweep B (tT)
                float2 t0 = *(const float2*)(sp + CS + (p0 + 0) * 34 + cp * 2);
                float2 t1 = *(const float2*)(sp + CS + (p0 + 1) * 34 + cp * 2);
                const int c0 = cp * 2, c1 = cp * 2 + 1;
                float4 wv0 = *(const float4*)(wL + 1024 + c0 * nC + d0);
                float4 wv1 = *(const float4*)(wL + 1024 + c1 * nC + d0);
                float4 ww0 = *(const float4*)(wL + 3072 + c0 * nC + d0);
                float4 ww1 = *(const float4*)(wL + 3072 + c1 * nC + d0);
                FMA4(accv[0], t0.x, wv0); FMA4(accv[1], t1.x, wv0);
                FMA4(accv[0], t0.y, wv1); FMA4(accv[1], t1.y, wv1);
                FMA4(accw[0], t0.x, ww0); FMA4(accw[1], t1.x, ww0);
                FMA4(accw[0], t0.y, ww1); FMA4(accw[1], t1.y, ww1);
            }
        }

        const int cb = base0 + k * CH;
        {   // epilogue v
            float4 b4 = *(const float4*)(bv + d0);
            #pragma unroll
            for (int l = 0; l < 2; ++l) {
                int p = cb + p0 + l;
                int b, i, j, m; decodePos(p, b, i, j, m);
                float4 d4 = *(const float4*)(drv + (size_t)((b * nN + i) * nN + m) * nC + d0);
                float4 c4 = *(const float4*)(ccv + (size_t)((b * nN + j) * nN + m) * nC + d0);
                float4 t4 = *(const float4*)(tbv + (size_t)(b * nN + m) * nC + d0);
                float mk = vm[b * nN + i] * vm[b * nN + j] * vm[b * nN + m];
                float4 o4;
                o4.x = (accv[l][0] + d4.x + c4.x + t4.x) * mk + b4.x;
                o4.y = (accv[l][1] + d4.y + c4.y + t4.y) * mk + b4.y;
                o4.z = (accv[l][2] + d4.z + c4.z + t4.z) * mk + b4.z;
                o4.w = (accv[l][3] + d4.w + c4.w + t4.w) * mk + b4.w;
                *(float4*)(vout + (size_t)p * nC + d0) = o4;
            }
        }
        {   // epilogue w
            float4 b4 = *(const float4*)(bw + d0);
            #pragma unroll
            for (int l = 0; l < 2; ++l) {
                int p = cb + p0 + l;
                int b, i, j, m; decodePos(p, b, i, j, m);
                float4 d4 = *(const float4*)(drw + (size_t)((b * nN + i) * nN + m) * nC + d0);
                float4 c4 = *(const float4*)(ccw + (size_t)((b * nN + j) * nN + m) * nC + d0);
                float4 t4 = *(const float4*)(tbw + (size_t)(b * nN + m) * nC + d0);
                float mk = vm[b * nN + i] * vm[b * nN + j] * vm[b * nN + m];
                float4 o4;
                o4.x = (accw[l][0] + d4.x + c4.x + t4.x) * mk + b4.x;
                o4.y = (accw[l][1] + d4.y + c4.y + t4.y) * mk + b4.y;
                o4.z = (accw[l][2] + d4.z + c4.z + t4.z) * mk + b4.z;
                o4.w = (accw[l][3] + d4.w + c4.w + t4.w) * mk + b4.w;
                *(float4*)(wout + (size_t)p * nC + d0) = o4;
            }
        }

        if (k < 8) {
            writeChunk((k + 1) & 1);           // other buffer: no race w/ readers
            __syncthreads();                   // next chunk visible to all
        }
    }
}

// ---------------------------------------------------------------------------
// z = V*W/n per (b,m); o-mix + relu + mask -> t; fused rows/cols/diag/tot
// partial reductions. R14: double-buffered K-staging (chunks of 4 k-slices,
// 2x6456-float buffers in the same LDS footprint; z-epilogue overlays after),
// register-staged loads issued before compute, ONE barrier per chunk.
// XCD-sibling swizzle: 4 tiles of one (b,m) -> same XCD (round-robin id&7).
__global__ __launch_bounds__(256, 3) void k_z(
    const float* __restrict__ v, const float* __restrict__ w,
    const float* __restrict__ Wo, const float* __restrict__ bo,
    const float* __restrict__ vm, float* __restrict__ tout,
    float* __restrict__ rows2, float* __restrict__ cols2,
    float* __restrict__ diag_, float* __restrict__ tot4)
{
    __shared__ float lds[12912];           // 51648 B -> 3 blocks/CU
    constexpr int HB = 6456;               // half-buffer (V 3228 + W 3228)
    constexpr int ZS = 34;                 // z/out row stride (per position)
    constexpr int ZWO = 9792;              // Wo area
    constexpr int TOT0 = 10816;            // tot scratch [8][32]
    const int tid = threadIdx.x;
    // XCD-sibling swizzle (bijective on [0,768)):
    const int idb = blockIdx.x;
    const int xcd = idb & 7; const int qq = idb >> 3;
    const int tl = qq & 3; const int bm = (qq >> 2) * 8 + xcd;
    const int it = tl >> 1, jt = tl & 1;
    const int b = bm / nN, m = bm % nN;
    const int c = tid & 31;
    const int g = tid >> 5;
    const int i3 = g >> 1, j2 = g & 1;     // i3 wave-uniform
    const int il0 = i3 * 6, jl0 = j2 * 12;
    const size_t posbase = (size_t)b * SB_ + (size_t)m * nC;

    // per-thread staging geometry (constant across chunks)
    const int q0 = tid, q1 = 256 + tid, q2 = 512 + tid;
    const int pV0 = q0 >> 3, pV1 = q1 >> 3, pV2 = q2 >> 3;
    const int cq0 = (q0 & 7) * 4, cq1 = (q1 & 7) * 4, cq2 = (q2 & 7) * 4;
    const int iiV0 = pV0 >> 2, kkV0 = pV0 & 3;
    const int iiV1 = pV1 >> 2, kkV1 = pV1 & 3;
    const int iiV2 = pV2 >> 2, kkV2 = pV2 & 3;
    const int kkW0 = pV0 / 24, jjW0 = pV0 - kkW0 * 24;
    const int kkW1 = pV1 / 24, jjW1 = pV1 - kkW1 * 24;
    const int kkW2 = pV2 / 24, jjW2 = pV2 - kkW2 * 24;
    const float* vs0 = v + posbase + (size_t)(it * 24 + iiV0) * SI_ + (size_t)kkV0 * SJ_ + cq0;
    const float* vs1 = v + posbase + (size_t)(it * 24 + iiV1) * SI_ + (size_t)kkV1 * SJ_ + cq1;
    const float* vs2 = v + posbase + (size_t)(it * 24 + iiV2) * SI_ + (size_t)kkV2 * SJ_ + cq2;
    const float* ws0 = w + posbase + (size_t)kkW0 * SI_ + (size_t)(jt * 24 + jjW0) * SJ_ + cq0;
    const float* ws1 = w + posbase + (size_t)kkW1 * SI_ + (size_t)(jt * 24 + jjW1) * SJ_ + cq1;
    const float* ws2 = w + posbase + (size_t)kkW2 * SI_ + (size_t)(jt * 24 + jjW2) * SJ_ + cq2;
    const int dV0 = kkV0 * 807 + cq0 * 25 + iiV0;
    const int dV1 = kkV1 * 807 + cq1 * 25 + iiV1;
    const int dV2 = kkV2 * 807 + cq2 * 25 + iiV2;
    const int dW0 = 3228 + kkW0 * 807 + cq0 * 25 + jjW0;
    const int dW1 = 3228 + kkW1 * 807 + cq1 * 25 + jjW1;
    const int dW2 = 3228 + kkW2 * 807 + cq2 * 25 + jjW2;

    float4 rv0, rv1, rv2, rw0, rw1, rw2;   // named: no scratch

    auto loadChunk = [&](int ch) {
        const size_t ov = (size_t)ch * 4 * SJ_;
        const size_t ow = (size_t)ch * 4 * SI_;
        rv0 = *(const float4*)(vs0 + ov);
        rv1 = *(const float4*)(vs1 + ov);
        rv2 = *(const float4*)(vs2 + ov);
        rw0 = *(const float4*)(ws0 + ow);
        rw1 = *(const float4*)(ws1 + ow);
        rw2 = *(const float4*)(ws2 + ow);
    };
    auto writeChunk = [&](int bufi) {
        float* bp = lds + bufi * HB;
        bp[dV0] = rv0.x; bp[dV0 + 25] = rv0.y; bp[dV0 + 50] = rv0.z; bp[dV0 + 75] = rv0.w;
        bp[dV1] = rv1.x; bp[dV1 + 25] = rv1.y; bp[dV1 + 50] = rv1.z; bp[dV1 + 75] = rv1.w;
        bp[dV2] = rv2.x; bp[dV2 + 25] = rv2.y; bp[dV2 + 50] = rv2.z; bp[dV2 + 75] = rv2.w;
        bp[dW0] = rw0.x; bp[dW0 + 25] = rw0.y; bp[dW0 + 50] = rw0.z; bp[dW0 + 75] = rw0.w;
        bp[dW1] = rw1.x; bp[dW1 + 25] = rw1.y; bp[dW1 + 50] = rw1.z; bp[dW1 + 75] = rw1.w;
        bp[dW2] = rw2.x; bp[dW2 + 25] = rw2.y; bp[dW2 + 50] = rw2.z; bp[dW2 + 75] = rw2.w;
    };

    float acc[6][12];
    #pragma unroll
    for (int l = 0; l < 6; ++l)
        #pragma unroll
        for (int u = 0; u < 12; ++u) acc[l][u] = 0.f;

    loadChunk(0);
    writeChunk(0);
    __syncthreads();

    for (int ch = 0; ch < 12; ++ch) {
        if (ch < 11) loadChunk(ch + 1);
        __builtin_amdgcn_sched_barrier(0);         // loads issued before compute
        const float* Vt = lds + (ch & 1) * HB;
        const float* Wt = Vt + 3228;
        #pragma unroll
        for (int kk = 0; kk < 4; ++kk) {
            float vf[6], wf[12];
            #pragma unroll
            for (int l = 0; l < 6; ++l) vf[l] = Vt[kk * 807 + c * 25 + il0 + l];
            #pragma unroll
            for (int u = 0; u < 12; ++u) wf[u] = Wt[kk * 807 + c * 25 + jl0 + u];
            #pragma unroll
            for (int l = 0; l < 6; ++l)
                #pragma unroll
                for (int u = 0; u < 12; ++u)
                    acc[l][u] = fmaf(vf[l], wf[u], acc[l][u]);
        }
        if (ch < 11) {
            writeChunk((ch + 1) & 1);              // other buffer: no race
            __syncthreads();                       // next chunk visible
        }
    }
    __syncthreads();                               // staging area now reusable

    #pragma unroll
    for (int e = 0; e < 4; ++e)                    // Wo * (1/48)
        lds[ZWO + e * 256 + tid] = Wo[e * 256 + tid] * (1.f / nN);

    const int ptE = tid >> 3, dqE = tid & 7, d0 = dqE * 4;
    const float4 b4 = *(const float4*)(bo + d0);
    const float vmm = vm[b * nN + m];
    float colacc[3] = {0.f, 0.f, 0.f};
    float totacc = 0.f;

    for (int h = 0; h < 2; ++h) {
        if (h) __syncthreads();                    // protect h=0 reduction reads
        if ((i3 >> 1) == h) {                      // write this half's z
            int r0 = il0 - 12 * h;                 // 0 or 6
            #pragma unroll
            for (int l = 0; l < 6; ++l)
                #pragma unroll
                for (int u = 0; u < 12; ++u)
                    lds[((r0 + l) * 24 + jl0 + u) * ZS + c] = acc[l][u];
        }
        __syncthreads();                           // z + wo visible

        float oac[9][4];
        #pragma unroll
        for (int u = 0; u < 9; ++u)
            #pragma unroll
            for (int d = 0; d < 4; ++d) oac[u][d] = 0.f;
        #pragma unroll
        for (int c2 = 0; c2 < 32; ++c2) {
            float4 wo4 = *(const float4*)(lds + ZWO + c2 * 32 + d0);
            float zv[9];
            #pragma unroll
            for (int u = 0; u < 9; ++u) zv[u] = lds[(ptE * 9 + u) * ZS + c2];
            #pragma unroll
            for (int u = 0; u < 9; ++u) {
                oac[u][0] = fmaf(zv[u], wo4.x, oac[u][0]);
                oac[u][1] = fmaf(zv[u], wo4.y, oac[u][1]);
                oac[u][2] = fmaf(zv[u], wo4.z, oac[u][2]);
                oac[u][3] = fmaf(zv[u], wo4.w, oac[u][3]);
            }
        }
        __syncthreads();                           // all z reads done

        #pragma unroll
        for (int u = 0; u < 9; ++u) {
            int p = ptE * 9 + u;
            int rl = p / 24, jl = p - rl * 24;
            int gi = it * 24 + 12 * h + rl, gj = jt * 24 + jl;
            float mk = vm[b * nN + gi] * vm[b * nN + gj] * vmm;
            float4 o4;
            o4.x = fmaxf(oac[u][0] + b4.x, 0.f) * mk;
            o4.y = fmaxf(oac[u][1] + b4.y, 0.f) * mk;
            o4.z = fmaxf(oac[u][2] + b4.z, 0.f) * mk;
            o4.w = fmaxf(oac[u][3] + b4.w, 0.f) * mk;
            *(float4*)(tout + posbase + (size_t)gi * SI_ + (size_t)gj * SJ_ + d0) = o4;
            *(float2*)(lds + p * ZS + d0) = make_float2(o4.x, o4.y);
            *(float2*)(lds + p * ZS + d0 + 2) = make_float2(o4.z, o4.w);
        }
        __syncthreads();                           // out tile visible in LDS

        for (int rd = 0; rd < 2; ++rd) {
            int task = rd * 256 + tid;
            if (task < 384) {
                int i_r = task >> 5, c_r = task & 31;
                float rsum = 0.f;
                #pragma unroll
                for (int jl = 0; jl < 24; ++jl) rsum += lds[(i_r * 24 + jl) * ZS + c_r];
                int gi = it * 24 + 12 * h + i_r;
                rows2[(size_t)jt * RP_ + ((size_t)(b * nN + gi) * nN + m) * nC + c_r] = rsum;
                totacc += rsum;
                if (it == jt)
                    diag_[((size_t)(b * nN + gi) * nN + m) * nC + c_r] =
                        lds[(i_r * 24 + (12 * h + i_r)) * ZS + c_r];
            }
        }
        #pragma unroll
        for (int rr = 0; rr < 3; ++rr) {
            int task = rr * 256 + tid;
            int jl = task >> 5, c_c = task & 31;
            float csum = 0.f;
            #pragma unroll
            for (int il = 0; il < 12; ++il) csum += lds[(il * 24 + jl) * ZS + c_c];
            colacc[rr] += csum;
        }
    }

    #pragma unroll
    for (int rr = 0; rr < 3; ++rr) {
        int task = rr * 256 + tid;
        int jl = task >> 5, c_c = task & 31;
        cols2[(size_t)it * CP_ + ((size_t)(b * nN + jt * 24 + jl) * nN + m) * nC + c_c] = colacc[rr];
    }
    lds[TOT0 + g * 32 + c] = totacc;
    __syncthreads();
    if (tid < 32) {
        float s = 0.f;
        #pragma unroll
        for (int gg = 0; gg < 8; ++gg) s += lds[TOT0 + gg * 32 + tid];
        tot4[(size_t)(it * 2 + jt) * TP_ + (size_t)(b * nN + m) * nC + tid] = s;
    }
}

// ---------------------------------------------------------------------------
// Final snconv2 (C_out = 16), masked, direct to d_out. Persistent-block
// pipelined like k_vw: 768 blocks x 9 chunks of 64 positions, dbuf LDS.
__global__ __launch_bounds__(256) void k_final(
    const float* __restrict__ t, const float* __restrict__ vm,
    const float* __restrict__ drp, const float* __restrict__ ccp, const float* __restrict__ tbp,
    const float* __restrict__ W0, const float* __restrict__ W1,
    float* __restrict__ out)
{
    constexpr int CH = 64, CS = CH * 34;
    __shared__ float sT[2][2 * CS];
    __shared__ float wL[1024];                 // [W0 | W1], 32x16 each
    const int tid = threadIdx.x;

    {
        float4* wl4 = (float4*)wL;
        for (int q = tid; q < 128; q += 256) wl4[q] = ((const float4*)W0)[q];
        for (int q = tid; q < 128; q += 256) wl4[128 + q] = ((const float4*)W1)[q];
    }

    const int base0 = blockIdx.x * 9 * CH;
    float4 rA0, rA1, rB0, rB1;

    auto loadChunk = [&](int k) {
        const int cb = base0 + k * CH;
        {   const int q = tid; const int pl = q >> 3, cq = q & 7;
            const int p = cb + pl;
            rA0 = *(const float4*)(t + (size_t)p * nC + cq * 4);
            int b, i, j, m; decodePos(p, b, i, j, m);
            long pT = ((long)(b * nN + j) * nN + i) * nN + m;
            rB0 = *(const float4*)(t + pT * nC + cq * 4);
        }
        {   const int q = 256 + tid; const int pl = q >> 3, cq = q & 7;
            const int p = cb + pl;
            rA1 = *(const float4*)(t + (size_t)p * nC + cq * 4);
            int b, i, j, m; decodePos(p, b, i, j, m);
            long pT = ((long)(b * nN + j) * nN + i) * nN + m;
            rB1 = *(const float4*)(t + pT * nC + cq * 4);
        }
    };
    auto writeChunk = [&](int buf) {
        {   const int q = tid; const int o = (q >> 3) * 34 + (q & 7) * 4;
            sT[buf][o + 0] = rA0.x; sT[buf][o + 1] = rA0.y;
            sT[buf][o + 2] = rA0.z; sT[buf][o + 3] = rA0.w;
            sT[buf][CS + o + 0] = rB0.x; sT[buf][CS + o + 1] = rB0.y;
            sT[buf][CS + o + 2] = rB0.z; sT[buf][CS + o + 3] = rB0.w;
        }
        {   const int q = 256 + tid; const int o = (q >> 3) * 34 + (q & 7) * 4;
            sT[buf][o + 0] = rA1.x; sT[buf][o + 1] = rA1.y;
            sT[buf][o + 2] = rA1.z; sT[buf][o + 3] = rA1.w;
            sT[buf][CS + o + 0] = rB1.x; sT[buf][CS + o + 1] = rB1.y;
            sT[buf][CS + o + 2] = rB1.z; sT[buf][CS + o + 3] = rB1.w;
        }
    };

    loadChunk(0);
    writeChunk(0);
    __syncthreads();

    const int pt = tid >> 3, dq = tid & 7;
    const int p0 = pt * 2, d0 = dq * 2;

    for (int k = 0; k < 9; ++k) {
        const int cur = k & 1;
        if (k < 8) loadChunk(k + 1);
        __builtin_amdgcn_sched_barrier(0);

        float acc[2][2];
        acc[0][0] = 0.f; acc[0][1] = 0.f; acc[1][0] = 0.f; acc[1][1] = 0.f;
        const float* sp = sT[cur];
        #pragma unroll
        for (int cp = 0; cp < 16; ++cp) {      // sweep A with W0
            float2 t0 = *(const float2*)(sp + (p0 + 0) * 34 + cp * 2);
            float2 t1 = *(const float2*)(sp + (p0 + 1) * 34 + cp * 2);
            const int c0 = cp * 2, c1 = cp * 2 + 1;
            float2 w0 = *(const float2*)(wL + c0 * 16 + d0);
            float2 w1 = *(const float2*)(wL + c1 * 16 + d0);
            acc[0][0] = fmaf(t0.x, w0.x, acc[0][0]); acc[0][1] = fmaf(t0.x, w0.y, acc[0][1]);
            acc[1][0] = fmaf(t1.x, w0.x, acc[1][0]); acc[1][1] = fmaf(t1.x, w0.y, acc[1][1]);
            acc[0][0] = fmaf(t0.y, w1.x, acc[0][0]); acc[0][1] = fmaf(t0.y, w1.y, acc[0][1]);
            acc[1][0] = fmaf(t1.y, w1.x, acc[1][0]); acc[1][1] = fmaf(t1.y, w1.y, acc[1][1]);
        }
        #pragma unroll
        for (int cp = 0; cp < 16; ++cp) {      // sweep B with W1
            float2 t0 = *(const float2*)(sp + CS + (p0 + 0) * 34 + cp * 2);
            float2 t1 = *(const float2*)(sp + CS + (p0 + 1) * 34 + cp * 2);
            const int c0 = cp * 2, c1 = cp * 2 + 1;
            float2 w0 = *(const float2*)(wL + 512 + c0 * 16 + d0);
            float2 w1 = *(const float2*)(wL + 512 + c1 * 16 + d0);
            acc[0][0] = fmaf(t0.x, w0.x, acc[0][0]); acc[0][1] = fmaf(t0.x, w0.y, acc[0][1]);
            acc[1][0] = fmaf(t1.x, w0.x, acc[1][0]); acc[1][1] = fmaf(t1.x, w0.y, acc[1][1]);
            acc[0][0] = fmaf(t0.y, w1.x, acc[0][0]); acc[0][1] = fmaf(t0.y, w1.y, acc[0][1]);
            acc[1][0] = fmaf(t1.y, w1.x, acc[1][0]); acc[1][1] = fmaf(t1.y, w1.y, acc[1][1]);
        }

        const int cb = base0 + k * CH;
        #pragma unroll
        for (int l = 0; l < 2; ++l) {
            int p = cb + p0 + l;
            int b, i, j, m; decodePos(p, b, i, j, m);
            float2 d2 = *(const float2*)(drp + (size_t)((b * nN + i) * nN + m) * 16 + d0);
            float2 cc2 = *(const float2*)(ccp + (size_t)((b * nN + j) * nN + m) * 16 + d0);
            float2 tb2 = *(const float2*)(tbp + (size_t)(b * nN + m) * 16 + d0);
            float mk = vm[b * nN + i] * vm[b * nN + j] * vm[b * nN + m];
            float2 o2;
            o2.x = (acc[l][0] + d2.x + cc2.x + tb2.x) * mk;
            o2.y = (acc[l][1] + d2.y + cc2.y + tb2.y) * mk;
            *(float2*)(out + (size_t)p * 16 + d0) = o2;
        }

        if (k < 8) {
            writeChunk((k + 1) & 1);
            __syncthreads();
        }
    }
}

} // anonymous namespace

// ---------------------------------------------------------------------------
extern "C" void kernel_launch(void* const* d_in, const int* in_sizes, int n_in,
                              void* d_out, int out_size, void* d_ws, size_t ws_size,
                              hipStream_t stream)
{
    (void)in_sizes; (void)n_in; (void)out_size; (void)ws_size;
    const float* x    = (const float*)d_in[0];
    const void*  mask = d_in[1];
    const float* bW0  = (const float*)d_in[2];
    const float* bb0  = (const float*)d_in[3];
    const float* lvW0 = (const float*)d_in[4];
    const float* lvb0 = (const float*)d_in[5];
    const float* lwW0 = (const float*)d_in[6];
    const float* lwb0 = (const float*)d_in[7];
    const float* loW0 = (const float*)d_in[8];
    const float* lob0 = (const float*)d_in[9];
    const float* bW1  = (const float*)d_in[10];
    const float* bb1  = (const float*)d_in[11];
    const float* lvW1 = (const float*)d_in[12];
    const float* lvb1 = (const float*)d_in[13];
    const float* lwW1 = (const float*)d_in[14];
    const float* lwb1 = (const float*)d_in[15];
    const float* loW1 = (const float*)d_in[16];
    const float* lob1 = (const float*)d_in[17];
    const float* fW   = (const float*)d_in[18];
    const float* fb   = (const float*)d_in[19];

    float* ws  = (float*)d_ws;
    float* t     = ws;                          // 14155776
    float* v     = ws + 14155776L;
    float* w     = ws + 28311552L;
    float* rows2 = ws + 42467328L;              // 2 * 294912
    float* cols2 = rows2 + 2 * 294912;          // 2 * 294912
    float* diag  = cols2 + 2 * 294912;          // 294912
    float* tot4  = diag + 294912;               // 4 * 6144
    float* drv   = tot4 + 4 * 6144;             // 294912
    float* ccv   = drv + 294912;                // 294912
    float* tbv   = ccv + 294912;                // 6144
    float* drw   = tbv + 6144;                  // 294912
    float* ccw   = drw + 294912;                // 294912
    float* tbw   = ccw + 294912;                // 6144
    float* cW    = tbw + 6144;                  // 4 * 6144 composed basic-W
    float* cb    = cW + 4 * 6144;               // 4 * 32 composed biases
    float* cWs   = cb + 128;                    // 2 * 1024 summed layer-0
    float* S     = cWs + 2048;                  // 128
    float* vm    = S + 128;                     // 192
    float* out   = (float*)d_out;

    k_prepcomp<<<5, 256, 0, stream>>>(x, mask, vm, S,
                                      bW0, bb0, lvW0, lwW0,
                                      bW1, bb1, lvW1, lwW1, cW, cb, cWs);

    // ---- layer 0 ----
    k_mix0<<<72, 256, 0, stream>>>(x, S,
                                   cW + 0,    cb + 0,  drv, ccv, tbv,
                                   cW + 6144, cb + 32, drw, ccw, tbw);
    k_vw<0><<<768, 256, 0, stream>>>(x, vm, drv, ccv, tbv, drw, ccw, tbw,
                                     cWs,        // [ (W0+W1)@Wv | (W0+W1)@Ww ]
                                     cWs,        // unused in MODE0
                                     lvb0, lwb0, v, w);
    k_z<<<768, 256, 0, stream>>>(v, w, loW0, lob0, vm, t, rows2, cols2, diag, tot4);

    // ---- layer 1 ----
    k_mix<32><<<72, 256, 0, stream>>>(diag, rows2, cols2, tot4,
                                      cW + 12288, cb + 64, drv, ccv, tbv,
                                      cW + 18432, cb + 96, drw, ccw, tbw);
    k_vw<1><<<768, 256, 0, stream>>>(t, vm, drv, ccv, tbv, drw, ccw, tbw,
                                     cW + 12288,  // [ W0@Wv | W1@Wv ]
                                     cW + 18432,  // [ W0@Ww | W1@Ww ]
                                     lvb1, lwb1, v, w);
    k_z<<<768, 256, 0, stream>>>(v, w, loW1, lob1, vm, t, rows2, cols2, diag, tot4);

    // ---- final snconv2 (uncomposed, 16ch) ----
    k_mix<16><<<36, 256, 0, stream>>>(diag, rows2, cols2, tot4,
                                      fW, fb, drv, ccv, tbv,
                                      fW, fb, drv, ccv, tbv);
    k_final<<<768, 256, 0, stream>>>(t, vm, drv, ccv, tbv, fW, fW + 512, out);
}